// Round 8
// baseline (1348.569 us; speedup 1.0000x reference)
//
#include <hip/hip_runtime.h>
#include <hip/hip_bf16.h>

#define NB 64
#define T1 3136
#define T2 784
#define T3 196
#define D1 147
#define D2 576

#define KP1 160   // padded K for W^T storage (front1)
#define KS1 168   // LDS row stride (bf16 elements), 16B-aligned rows
#define KQS 68    // kqs row stride (floats) — breaks 64-stride bank alias

typedef __attribute__((ext_vector_type(8))) short bf16x8;
typedef __attribute__((ext_vector_type(4))) float f32x4;

__device__ __forceinline__ float waveReduceSum(float v) {
#pragma unroll
    for (int off = 32; off > 0; off >>= 1) v += __shfl_down(v, off, 64);
    return __shfl(v, 0, 64);
}

__device__ __forceinline__ unsigned short f2bf(float v) {
    unsigned int u = __float_as_uint(v);
    return (unsigned short)((u + 0x7FFFu + ((u >> 16) & 1u)) >> 16);
}

// ---------------------------------------------------------------------------
// prep kernels.
// prep_scale: W2g[d,c] = kqv_w[d,c]*ln_g[d] (front2 folded-LN weights).
// prep_sums:  S2[c] = sum_d w[d,c]*g[d]; S3[c] = sum_d w[d,c]*b[d] + kqv_b[c].
// prep_wt:    split-bf16 W^T for front1 MFMA: wt[n][k] = bf16 split of
//             kqv_w[k][n]*ln_g[k], zero-padded to K=KP1.
// ---------------------------------------------------------------------------
__global__ __launch_bounds__(256) void prep_scale(
    const float* __restrict__ w, const float* __restrict__ g,
    float* __restrict__ w2, int D)
{
    const int i = blockIdx.x * 256 + threadIdx.x;
    if (i < D * 192) w2[i] = w[i] * g[i / 192];
}

__global__ __launch_bounds__(192) void prep_sums(
    const float* __restrict__ w, const float* __restrict__ g,
    const float* __restrict__ bb, const float* __restrict__ kqvb,
    float* __restrict__ s2, float* __restrict__ s3, int D)
{
    const int col = threadIdx.x;
    float a2 = 0.f, a3 = 0.f;
    for (int d = 0; d < D; ++d) {
        const float wv = w[d * 192 + col];
        a2 += wv * g[d];
        a3 += wv * bb[d];
    }
    s2[col] = a2; s3[col] = a3 + kqvb[col];
}

__global__ __launch_bounds__(256) void prep_wt(
    const float* __restrict__ w, const float* __restrict__ g,
    unsigned short* __restrict__ hi, unsigned short* __restrict__ lo,
    int D, int K)
{
    const int i = blockIdx.x * 256 + threadIdx.x;
    if (i >= 192 * K) return;
    const int n = i / K, k = i % K;
    const float v = (k < D) ? w[k * 192 + n] * g[k] : 0.f;
    const unsigned short h = f2bf(v);
    const float hf = __uint_as_float((unsigned int)h << 16);
    hi[i] = h;
    lo[i] = f2bf(v - hf);
}

// ---------------------------------------------------------------------------
// front1 v6 (MFMA): 32 tokens/block, 256 threads = 4 waves.
// unfold(7,4,2) -> bf16 hi/lo in LDS (LN stats fused in registers) ->
// split-precision bf16 MFMA matvec (xh*wh + xl*wh + xh*wl; rel err ~2^-17)
// -> fold-correction epilogue from C fragments -> prm_exp (unchanged).
// Wave w owns N-tiles {3w,3w+1,3w+2} x M-tiles {0,1}; K = 5 steps of 32.
// C/D layout per m89: col=lane&15, row=4*(lane>>4)+reg. The k-mapping of
// A/B fragments cancels (same bijection on both operands), so only the
// M-row (=lane&15) mapping is assumed.
// ---------------------------------------------------------------------------
__global__ __launch_bounds__(256) void front1(
    const float* __restrict__ x,
    const unsigned short* __restrict__ wt_hi,  // (192,KP1) bf16 W^T hi
    const unsigned short* __restrict__ wt_lo,  // (192,KP1) bf16 W^T lo
    const float* __restrict__ s2v,     // (192)
    const float* __restrict__ s3v,     // (192)
    const float* __restrict__ rf,      // (32,64)
    float* __restrict__ kp, float* __restrict__ qp,   // (B*T1,32)
    float* __restrict__ v_out)                        // (B*T1,64)
{
    const int tok0 = blockIdx.x * 32;
    const int b = tok0 / T1;
    const int tbase = tok0 % T1;
    const int tid = threadIdx.x;
    const int wv = tid >> 6, l = tid & 63;
    const int l15 = l & 15, lg = l >> 4;

    __shared__ __align__(16) unsigned short Abuf[2 * 32 * KS1];  // 21504B
    __shared__ float ps_sum[256], ps_sq[256];
    __shared__ float mu_s[32], rs_s[32], xd_s[64];

    unsigned short* A_hi = Abuf;
    unsigned short* A_lo = Abuf + 32 * KS1;
    float* kqs = (float*)Abuf;                 // 64*KQS floats = 17408B, aliases

    // --- fill: raw unfold -> bf16 hi/lo, LN stats in registers ---
    { const int m = tid & 31, j = tid >> 5;    // token, d-slice (8 slices)
      const int t = tbase + m;
      const int py = t / 56, px = t % 56;
      const int iy0 = py * 4 - 2, ix0 = px * 4 - 2;
      float sm = 0.f, sq = 0.f;
      for (int d = j; d < KS1; d += 8) {
          float val = 0.f;
          if (d < D1) {
              const int cc = d / 49, r = d % 49, ki = r / 7, kj = r % 7;
              const int iy = iy0 + ki, ix = ix0 + kj;
              if (iy >= 0 && iy < 224 && ix >= 0 && ix < 224)
                  val = x[((b * 3 + cc) * 224 + iy) * 224 + ix];
          }
          sm += val; sq += val * val;
          const unsigned short h = f2bf(val);
          const float hf = __uint_as_float((unsigned int)h << 16);
          A_hi[m * KS1 + d] = h;
          A_lo[m * KS1 + d] = f2bf(val - hf);
      }
      ps_sum[tid] = sm; ps_sq[tid] = sq; }
    __syncthreads();                           // barrier A: A + stats ready
    if (tid < 32) {
        float s = 0.f, s2 = 0.f;
#pragma unroll
        for (int j2 = 0; j2 < 8; ++j2) { s += ps_sum[j2*32+tid]; s2 += ps_sq[j2*32+tid]; }
        const float mu = s * (1.f / D1);
        mu_s[tid] = mu; rs_s[tid] = rsqrtf(s2 * (1.f / D1) - mu * mu + 1e-5f);
    }

    // --- MFMA matvec ---
    f32x4 acc[2][3];
    { const f32x4 z = {0.f, 0.f, 0.f, 0.f};
#pragma unroll
      for (int mt = 0; mt < 2; ++mt)
#pragma unroll
        for (int nt = 0; nt < 3; ++nt) acc[mt][nt] = z; }

    const int colb = 48 * wv + l15;
#pragma unroll
    for (int ks = 0; ks < 5; ++ks) {
        const int ko = ks * 32 + 8 * lg;
        const bf16x8 ah0 = *(const bf16x8*)&A_hi[l15 * KS1 + ko];
        const bf16x8 ah1 = *(const bf16x8*)&A_hi[(16 + l15) * KS1 + ko];
        const bf16x8 al0 = *(const bf16x8*)&A_lo[l15 * KS1 + ko];
        const bf16x8 al1 = *(const bf16x8*)&A_lo[(16 + l15) * KS1 + ko];
#pragma unroll
        for (int nt = 0; nt < 3; ++nt) {
            const size_t wo = (size_t)(colb + 16 * nt) * KP1 + ko;
            const bf16x8 bh = *(const bf16x8*)&wt_hi[wo];
            const bf16x8 bl = *(const bf16x8*)&wt_lo[wo];
            acc[0][nt] = __builtin_amdgcn_mfma_f32_16x16x32_bf16(ah0, bh, acc[0][nt], 0, 0, 0);
            acc[1][nt] = __builtin_amdgcn_mfma_f32_16x16x32_bf16(ah1, bh, acc[1][nt], 0, 0, 0);
            acc[0][nt] = __builtin_amdgcn_mfma_f32_16x16x32_bf16(al0, bh, acc[0][nt], 0, 0, 0);
            acc[1][nt] = __builtin_amdgcn_mfma_f32_16x16x32_bf16(al1, bh, acc[1][nt], 0, 0, 0);
            acc[0][nt] = __builtin_amdgcn_mfma_f32_16x16x32_bf16(ah0, bl, acc[0][nt], 0, 0, 0);
            acc[1][nt] = __builtin_amdgcn_mfma_f32_16x16x32_bf16(ah1, bl, acc[1][nt], 0, 0, 0);
        }
    }
    __syncthreads();                           // barrier B: A free, mu_s visible

    // --- fold-correction + scatter from C fragments ---
#pragma unroll
    for (int nt = 0; nt < 3; ++nt) {
        const int col = colb + 16 * nt;
        const int third = col >> 6, cc = col & 63;
        const float s2c = s2v[col], s3c = s3v[col];
#pragma unroll
        for (int mt = 0; mt < 2; ++mt) {
#pragma unroll
            for (int r = 0; r < 4; ++r) {
                const int token = mt * 16 + 4 * lg + r;
                const float o = rs_s[token] * (acc[mt][nt][r] - mu_s[token] * s2c) + s3c;
                if (third == 2)
                    v_out[(size_t)(tok0 + token) * 64 + cc] = o;
                else
                    kqs[(third * 32 + token) * KQS + cc] = o;
            }
        }
    }
    __syncthreads();

    // xd (0.5*||row||^2) from kqs: 256 threads x 16-col segments
    { const int hm = tid >> 2, seg = tid & 3;
      const float* kr = &kqs[hm * KQS + seg * 16];
      float s = 0.f;
#pragma unroll
      for (int c2 = 0; c2 < 16; ++c2) { const float t2 = kr[c2]; s += t2 * t2; }
      ps_sum[tid] = s; }
    __syncthreads();
    if (tid < 64)
        xd_s[tid] = 0.5f * (ps_sum[4*tid] + ps_sum[4*tid+1] + ps_sum[4*tid+2] + ps_sum[4*tid+3]);
    __syncthreads();

    float4 rfr[16];
    { const float* rp = rf + (size_t)(tid & 31) * 64;
#pragma unroll
      for (int g = 0; g < 16; ++g) rfr[g] = *(const float4*)(rp + 4 * g); }

    for (int slot = tid; slot < 2048; slot += 256) {
        const int half = slot >> 10, rem = slot & 1023;
        const int m = rem >> 5, mrf = slot & 31;
        const float4* k4 = (const float4*)&kqs[(half * 32 + m) * KQS];
        float a = 0.f;
#pragma unroll
        for (int g = 0; g < 16; ++g) {
            const float4 kv = k4[g];
            a += rfr[g].x*kv.x + rfr[g].y*kv.y + rfr[g].z*kv.z + rfr[g].w*kv.w;
        }
        const float p = expf(a - xd_s[half * 32 + m]) * 0.1767766952966369f;
        (half ? qp : kp)[(size_t)(tok0 + m) * 32 + mrf] = p;
    }
}

// 4-row FMA block for front2 (reads bufk, accumulates into acc)
#define F2_COMPUTE(DG, W0, W1, W2)                                            \
    _Pragma("unroll")                                                         \
    for (int i = 0; i < 4; ++i) {                                             \
        const int dl = (DG) * 4 + i;                                          \
        const float4 f0 = *(const float4*)&bufk[dl * 20 + 8 * tg];            \
        const float4 f1 = *(const float4*)&bufk[dl * 20 + 8 * tg + 4];        \
        acc[0][0] += f0.x*W0[i]; acc[0][1] += f0.y*W0[i]; acc[0][2] += f0.z*W0[i]; acc[0][3] += f0.w*W0[i]; \
        acc[0][4] += f1.x*W0[i]; acc[0][5] += f1.y*W0[i]; acc[0][6] += f1.z*W0[i]; acc[0][7] += f1.w*W0[i]; \
        acc[1][0] += f0.x*W1[i]; acc[1][1] += f0.y*W1[i]; acc[1][2] += f0.z*W1[i]; acc[1][3] += f0.w*W1[i]; \
        acc[1][4] += f1.x*W1[i]; acc[1][5] += f1.y*W1[i]; acc[1][6] += f1.z*W1[i]; acc[1][7] += f1.w*W1[i]; \
        acc[2][0] += f0.x*W2[i]; acc[2][1] += f0.y*W2[i]; acc[2][2] += f0.z*W2[i]; acc[2][3] += f0.w*W2[i]; \
        acc[2][4] += f1.x*W2[i]; acc[2][5] += f1.y*W2[i]; acc[2][6] += f1.z*W2[i]; acc[2][7] += f1.w*W2[i]; \
    }

// ---------------------------------------------------------------------------
// front2 v4: 16 tokens/block, 128 threads, 8 x 72-row chunks double-buffered.
// No min-waves clamp; role-alternating weight pairs.
// ---------------------------------------------------------------------------
__global__ __launch_bounds__(128) void front2(
    const float* __restrict__ src,     // o1 (B*T1,64)
    const float* __restrict__ w2g,     // (576,192) pre-scaled
    const float* __restrict__ s2v,     // (192)
    const float* __restrict__ s3v,     // (192)
    const float* __restrict__ rf,
    float* __restrict__ kp, float* __restrict__ qp,   // (B*T2,32)
    float* __restrict__ v_out)                        // (B*T2,64)
{
    const int tok0 = blockIdx.x * 16;
    const int b = tok0 / T2;
    const int tbase = tok0 % T2;   // T2 % 16 == 0
    const int tid = threadIdx.x;
    const int c = tid & 63, tg = tid >> 6;
    const int lane = tid & 63;
    const int ch = tid & 7;

    __shared__ __align__(16) float buf[2][72 * 20];   // 11.25KB double buffer
    __shared__ float ps_sum[128], ps_sq[128];
    __shared__ float mu_s[16], rs_s[16];
    __shared__ float xd_s[32];

    float* kqs = &buf[0][0];    // [2][16][64] = 2048 floats <= 2880, aliases buf

    const int g16 = tid >> 3;                 // token owned by this thread
    const int tmine = tbase + g16;
    const int py = tmine / 28, px = tmine % 28;
    const int iy0 = py * 2 - 1, ix0 = px * 2 - 1;
    const float* srcb = src + (size_t)b * T1 * 64 + ch;

    float acc[3][8];
#pragma unroll
    for (int i = 0; i < 3; ++i)
#pragma unroll
        for (int m = 0; m < 8; ++m) acc[i][m] = 0.f;   // bias folded into S3
    float sm = 0.f, sq = 0.f;                           // LN partials (token g16, channel ch)

#pragma unroll
    for (int r = 0; r < 9; ++r) {
        const int iy = iy0 + r / 3, ix = ix0 + r % 3;
        float val = 0.f;
        if (iy >= 0 && iy < 56 && ix >= 0 && ix < 56)
            val = srcb[(size_t)(iy * 56 + ix) * 64];
        sm += val; sq += val * val;
        buf[0][(ch * 9 + r) * 20 + g16] = val;
    }
    __syncthreads();

    float w0[4], w1[4], w2[4], n0[4], n1[4], n2[4];
    { const float* wp = w2g + c;
#pragma unroll
      for (int i = 0; i < 4; ++i) { w0[i] = wp[i*192]; w1[i] = wp[i*192+64]; w2[i] = wp[i*192+128]; } }

    for (int k = 0; k < 8; ++k) {
        float fv[9];
        if (k < 7) {
            const int c0 = (k + 1) * 8;
#pragma unroll
            for (int r = 0; r < 9; ++r) {
                const int iy = iy0 + r / 3, ix = ix0 + r % 3;
                float val = 0.f;
                if (iy >= 0 && iy < 56 && ix >= 0 && ix < 56)
                    val = srcb[(size_t)(iy * 56 + ix) * 64 + c0];
                fv[r] = val;
                sm += val; sq += val * val;
            }
        }

        const float* bufk = buf[k & 1];
        for (int p = 0; p < 9; ++p) {
            const int growA = k * 72 + p * 8;                   // rows of dg 2p
            { const float* wp = w2g + (size_t)(growA + 4) * 192 + c;   // dg 2p+1 -> n
#pragma unroll
              for (int i = 0; i < 4; ++i) { n0[i] = wp[i*192]; n1[i] = wp[i*192+64]; n2[i] = wp[i*192+128]; } }
            F2_COMPUTE(2 * p, w0, w1, w2)                       // dg 2p from w
            if (growA + 8 < D2) {
                const float* wp = w2g + (size_t)(growA + 8) * 192 + c; // dg 2p+2 -> w
#pragma unroll
                for (int i = 0; i < 4; ++i) { w0[i] = wp[i*192]; w1[i] = wp[i*192+64]; w2[i] = wp[i*192+128]; }
            }
            F2_COMPUTE(2 * p + 1, n0, n1, n2)                   // dg 2p+1 from n
        }

        if (k < 7) {
            float* bufn = buf[(k + 1) & 1];
#pragma unroll
            for (int r = 0; r < 9; ++r)
                bufn[(ch * 9 + r) * 20 + g16] = fv[r];
        }
        __syncthreads();
    }

    ps_sum[tid] = sm; ps_sq[tid] = sq;
    __syncthreads();
    if (tid < 16) {
        float s = 0.f, s2 = 0.f;
        for (int j = 0; j < 8; ++j) { s += ps_sum[tid * 8 + j]; s2 += ps_sq[tid * 8 + j]; }
        const float mu = s * (1.f / D2);
        const float var = s2 * (1.f / D2) - mu * mu;
        mu_s[tid] = mu; rs_s[tid] = rsqrtf(var + 1e-5f);
    }
    __syncthreads();

    { float s2c[3], s3c[3];
#pragma unroll
      for (int i = 0; i < 3; ++i) { s2c[i] = s2v[c + 64*i]; s3c[i] = s3v[c + 64*i]; }
#pragma unroll
      for (int m = 0; m < 8; ++m) {
          const int tm = 8 * tg + m;
          const float mu = mu_s[tm], rs = rs_s[tm];
#pragma unroll
          for (int i = 0; i < 3; ++i)
              acc[i][m] = rs * (acc[i][m] - mu * s2c[i]) + s3c[i];
      } }

#pragma unroll
    for (int m = 0; m < 8; ++m)
        v_out[(size_t)(tok0 + 8 * tg + m) * 64 + c] = acc[2][m];
#pragma unroll
    for (int m = 0; m < 8; ++m) {
        kqs[(0 * 16 + 8 * tg + m) * 64 + c] = acc[0][m];
        kqs[(1 * 16 + 8 * tg + m) * 64 + c] = acc[1][m];
    }
#pragma unroll
    for (int m = 0; m < 8; ++m) {
        const float sk = waveReduceSum(acc[0][m] * acc[0][m]);
        const float sq2 = waveReduceSum(acc[1][m] * acc[1][m]);
        if (lane == 0) { xd_s[8 * tg + m] = 0.5f * sk; xd_s[16 + 8 * tg + m] = 0.5f * sq2; }
    }
    __syncthreads();

    float4 rfr[16];
    { const float* rp = rf + (size_t)(tid & 31) * 64;
#pragma unroll
      for (int g = 0; g < 16; ++g) rfr[g] = *(const float4*)(rp + 4 * g); }

    for (int slot = tid; slot < 1024; slot += 128) {
        const int half = slot >> 9, rem = slot & 511;
        const int m = rem >> 5, mrf = slot & 31;
        const float4* k4 = (const float4*)&kqs[(half * 16 + m) * 64];
        float a = 0.f;
#pragma unroll
        for (int g = 0; g < 16; ++g) {
            const float4 kv = k4[g];
            a += rfr[g].x*kv.x + rfr[g].y*kv.y + rfr[g].z*kv.z + rfr[g].w*kv.w;
        }
        const float p = expf(a - xd_s[half * 16 + m]) * 0.1767766952966369f;
        (half ? qp : kp)[(size_t)(tok0 + m) * 32 + mrf] = p;
    }
}

// ---------------------------------------------------------------------------
// reduce_kv, split S-ways over T with atomics (ksum/kptv pre-zeroed)
// ---------------------------------------------------------------------------
template <int T, int S>
__global__ __launch_bounds__(256) void reduce_kv(
    const float* __restrict__ kp, const float* __restrict__ v,
    float* __restrict__ ksum, float* __restrict__ kptv)
{
    const int b = blockIdx.x / S, s = blockIdx.x % S;
    const int chunk = T / S;
    const int tid = threadIdx.x;
    __shared__ float kp_s[8][32];
    __shared__ float v_s[8][64];
    float acc[8] = {0.f, 0.f, 0.f, 0.f, 0.f, 0.f, 0.f, 0.f};
    float ks = 0.f;
    const int n = tid >> 2;
    const int mb = (tid & 3) * 8;
    const float* kpb = kp + (size_t)b * T * 32;
    const float* vb  = v  + (size_t)b * T * 64;

    for (int t0 = s * chunk; t0 < (s + 1) * chunk; t0 += 8) {
        kp_s[tid >> 5][tid & 31] = kpb[(t0 + (tid >> 5)) * 32 + (tid & 31)];
        {
            const int i0 = tid * 2, i1 = tid * 2 + 1;
            v_s[i0 >> 6][i0 & 63] = vb[(t0 + (i0 >> 6)) * 64 + (i0 & 63)];
            v_s[i1 >> 6][i1 & 63] = vb[(t0 + (i1 >> 6)) * 64 + (i1 & 63)];
        }
        __syncthreads();
#pragma unroll
        for (int tt = 0; tt < 8; ++tt) {
            const float vv = v_s[tt][n];
#pragma unroll
            for (int i = 0; i < 8; ++i) acc[i] += vv * kp_s[tt][mb + i];
        }
        if (tid < 32) {
#pragma unroll
            for (int tt = 0; tt < 8; ++tt) ks += kp_s[tt][tid];
        }
        __syncthreads();
    }
#pragma unroll
    for (int i = 0; i < 8; ++i) atomicAdd(&kptv[(b * 64 + n) * 32 + mb + i], acc[i]);
    if (tid < 32) atomicAdd(&ksum[b * 32 + tid], ks);
}

// ---------------------------------------------------------------------------
// epilogue: 128 threads = two independent 16-token tiles; per-sub ksum.
// ---------------------------------------------------------------------------
template <int T>
__global__ __launch_bounds__(128) void epilogue(
    const float* __restrict__ qp, const float* __restrict__ v,
    const float* __restrict__ ksum, const float* __restrict__ kptv,
    const float* __restrict__ proj_w, const float* __restrict__ proj_b,
    const float* __restrict__ ln2_g, const float* __restrict__ ln2_b,
    const float* __restrict__ m1_w, const float* __restrict__ m1_b,
    const float* __restrict__ m2_w, const float* __restrict__ m2_b,
    float* __restrict__ out)
{
    const int sub = threadIdx.x >> 6;
    const int e = threadIdx.x & 63;
    const int tok0 = blockIdx.x * 32 + sub * 16;
    const int b = tok0 / T;

    __shared__ __align__(16) float qp_s[2][16 * 36];
    __shared__ __align__(16) float buf[2][64 * 20];
    __shared__ float ks_s[2][32];
    __shared__ float D_s[2][16];

    for (int idx = e; idx < 512; idx += 64)
        qp_s[sub][(idx >> 5) * 36 + (idx & 31)] = qp[(size_t)tok0 * 32 + idx];
    if (e < 32) ks_s[sub][e] = ksum[b * 32 + e];
    __syncthreads();
    if (e < 16) {
        float D = 1e-8f;
        for (int r = 0; r < 32; ++r) D += qp_s[sub][e * 36 + r] * ks_s[sub][r];
        D_s[sub][e] = D;
    }
    float4 kv4[8];
#pragma unroll
    for (int g = 0; g < 8; ++g)
        kv4[g] = *(const float4*)&kptv[(size_t)(b * 64 + e) * 32 + 4 * g];
    __syncthreads();

    float ya[16];
#pragma unroll
    for (int m = 0; m < 16; ++m) {
        const float4* q4 = (const float4*)&qp_s[sub][m * 36];
        float a = 0.f;
#pragma unroll
        for (int g = 0; g < 8; ++g) {
            const float4 qv = q4[g];
            a += qv.x*kv4[g].x + qv.y*kv4[g].y + qv.z*kv4[g].z + qv.w*kv4[g].w;
        }
        ya[m] = a / D_s[sub][m];
    }
#pragma unroll
    for (int g = 0; g < 4; ++g)
        *(float4*)&buf[sub][e * 20 + 4*g] = make_float4(ya[4*g], ya[4*g+1], ya[4*g+2], ya[4*g+3]);
    __syncthreads();

    float y[16];
    { float acc2[16];
      const float pb = proj_b[e];
#pragma unroll
      for (int m = 0; m < 16; ++m) acc2[m] = pb;
      for (int j = 0; j < 64; ++j) {
          const float w = proj_w[j * 64 + e];
          const float4* a4 = (const float4*)&buf[sub][j * 20];
#pragma unroll
          for (int g = 0; g < 4; ++g) {
              const float4 av = a4[g];
              acc2[4*g+0] += av.x * w; acc2[4*g+1] += av.y * w;
              acc2[4*g+2] += av.z * w; acc2[4*g+3] += av.w * w;
          }
      }
#pragma unroll
      for (int m = 0; m < 16; ++m)
          y[m] = v[(size_t)(tok0 + m) * 64 + e] + acc2[m];
    }
    __syncthreads();

    { const float g2 = ln2_g[e], bb = ln2_b[e];
      float z[16];
#pragma unroll
      for (int m = 0; m < 16; ++m) {
          const float s  = waveReduceSum(y[m]);
          const float s2 = waveReduceSum(y[m] * y[m]);
          const float mu = s * (1.f / 64.f);
          const float var = s2 * (1.f / 64.f) - mu * mu;
          z[m] = (y[m] - mu) * rsqrtf(var + 1e-5f) * g2 + bb;
      }
#pragma unroll
      for (int g = 0; g < 4; ++g)
          *(float4*)&buf[sub][e * 20 + 4*g] = make_float4(z[4*g], z[4*g+1], z[4*g+2], z[4*g+3]);
    }
    __syncthreads();

    float h[16];
    { const float b1 = m1_b[e];
#pragma unroll
      for (int m = 0; m < 16; ++m) h[m] = b1;
      for (int j = 0; j < 64; ++j) {
          const float w = m1_w[j * 64 + e];
          const float4* a4 = (const float4*)&buf[sub][j * 20];
#pragma unroll
          for (int g = 0; g < 4; ++g) {
              const float4 av = a4[g];
              h[4*g+0] += av.x * w; h[4*g+1] += av.y * w;
              h[4*g+2] += av.z * w; h[4*g+3] += av.w * w;
          }
      }
#pragma unroll
      for (int m = 0; m < 16; ++m)
          h[m] = 0.5f * h[m] * (1.f + erff(h[m] * 0.7071067811865476f));
    }
    __syncthreads();
#pragma unroll
    for (int g = 0; g < 4; ++g)
        *(float4*)&buf[sub][e * 20 + 4*g] = make_float4(h[4*g], h[4*g+1], h[4*g+2], h[4*g+3]);
    __syncthreads();

    { const float b2v = m2_b[e];
      float acc4[16];
#pragma unroll
      for (int m = 0; m < 16; ++m) acc4[m] = b2v;
      for (int j = 0; j < 64; ++j) {
          const float w = m2_w[j * 64 + e];
          const float4* a4 = (const float4*)&buf[sub][j * 20];
#pragma unroll
          for (int g = 0; g < 4; ++g) {
              const float4 av = a4[g];
              acc4[4*g+0] += av.x * w; acc4[4*g+1] += av.y * w;
              acc4[4*g+2] += av.z * w; acc4[4*g+3] += av.w * w;
          }
      }
#pragma unroll
      for (int m = 0; m < 16; ++m)
          out[(size_t)(tok0 + m) * 64 + e] = y[m] + acc4[m];
    }
}

// 4-row FMA block for final_proj
#define FP_COMPUTE(DG, W0, W1, W2)                                            \
    _Pragma("unroll")                                                         \
    for (int i = 0; i < 4; ++i) {                                             \
        const int dl = (DG) * 4 + i;                                          \
        const float4* f4 = (const float4*)&bufk[dl * 20];                     \
        _Pragma("unroll")                                                     \
        for (int g = 0; g < 4; ++g) {                                         \
            const float4 f = f4[g];                                           \
            acc[0][4*g+0] += f.x * W0[i]; acc[0][4*g+1] += f.y * W0[i];       \
            acc[0][4*g+2] += f.z * W0[i]; acc[0][4*g+3] += f.w * W0[i];       \
            acc[1][4*g+0] += f.x * W1[i]; acc[1][4*g+1] += f.y * W1[i];       \
            acc[1][4*g+2] += f.z * W1[i]; acc[1][4*g+3] += f.w * W1[i];       \
            acc[2][4*g+0] += f.x * W2[i]; acc[2][4*g+1] += f.y * W2[i];       \
            acc[2][4*g+2] += f.z * W2[i]; acc[2][4*g+3] += f.w * W2[i];       \
        }                                                                     \
    }

// ---------------------------------------------------------------------------
// final: unfold(3,2,1) from o2 + dense 576->768. 16 tokens/block, 256 threads.
// ---------------------------------------------------------------------------
__global__ __launch_bounds__(256) void final_proj(
    const float* __restrict__ o2,    // (B*T2,64)
    const float* __restrict__ w,     // (576,768)
    const float* __restrict__ bias,  // (768)
    float* __restrict__ out)         // (B*T3,768)
{
    const int tok0 = blockIdx.x * 16;
    const int tid = threadIdx.x;
    const int cl = tid & 15, grp = tid >> 4;   // 16 ch x 16 grp

    __shared__ __align__(16) float buf[2][144 * 20];

    float acc[3][16];
    { const float b0 = bias[tid], b1 = bias[tid + 256], b2 = bias[tid + 512];
#pragma unroll
      for (int m = 0; m < 16; ++m) { acc[0][m] = b0; acc[1][m] = b1; acc[2][m] = b2; } }

#pragma unroll
    for (int ii = 0; ii < 9; ++ii) {
        const int u = grp + ii * 16;         // m*9 + r
        const int m = u / 9, r = u % 9;
        const int tok = tok0 + m, bb = tok / T3, tt = tok % T3;
        const int py = tt / 14, px = tt % 14;
        const int iy = py * 2 - 1 + r / 3, ix = px * 2 - 1 + r % 3;
        float val = 0.f;
        if (iy >= 0 && iy < 28 && ix >= 0 && ix < 28)
            val = o2[(size_t)(bb * T2 + iy * 28 + ix) * 64 + cl];
        buf[0][(cl * 9 + r) * 20 + m] = val;
    }
    __syncthreads();

    float w0[4], w1[4], w2[4], n0[4], n1[4], n2[4];
    { const float* wp = w + tid;             // dg 0 -> w
#pragma unroll
      for (int i = 0; i < 4; ++i) { w0[i] = wp[i*768]; w1[i] = wp[i*768+256]; w2[i] = wp[i*768+512]; } }

    for (int k = 0; k < 4; ++k) {
        float fv[9];
        if (k < 3) {
            const int c0 = (k + 1) * 16;
#pragma unroll
            for (int ii = 0; ii < 9; ++ii) {
                const int u = grp + ii * 16;
                const int m = u / 9, r = u % 9;
                const int tok = tok0 + m, bb = tok / T3, tt = tok % T3;
                const int py = tt / 14, px = tt % 14;
                const int iy = py * 2 - 1 + r / 3, ix = px * 2 - 1 + r % 3;
                float val = 0.f;
                if (iy >= 0 && iy < 28 && ix >= 0 && ix < 28)
                    val = o2[(size_t)(bb * T2 + iy * 28 + ix) * 64 + c0 + cl];
                fv[ii] = val;
            }
        }

        const float* bufk = buf[k & 1];
        for (int p = 0; p < 18; ++p) {
            const int growA = k * 144 + p * 8;                  // rows of dg 2p
            { const float* wp = w + (size_t)(growA + 4) * 768 + tid;   // dg 2p+1 -> n
#pragma unroll
              for (int i = 0; i < 4; ++i) { n0[i] = wp[i*768]; n1[i] = wp[i*768+256]; n2[i] = wp[i*768+512]; } }
            FP_COMPUTE(2 * p, w0, w1, w2)                       // dg 2p from w
            if (growA + 8 < D2) {
                const float* wp = w + (size_t)(growA + 8) * 768 + tid; // dg 2p+2 -> w
#pragma unroll
                for (int i = 0; i < 4; ++i) { w0[i] = wp[i*768]; w1[i] = wp[i*768+256]; w2[i] = wp[i*768+512]; }
            }
            FP_COMPUTE(2 * p + 1, n0, n1, n2)                   // dg 2p+1 from n
        }

        if (k < 3) {
            float* bufn = buf[(k + 1) & 1];
#pragma unroll
            for (int ii = 0; ii < 9; ++ii) {
                const int u = grp + ii * 16;
                bufn[(cl * 9 + u % 9) * 20 + u / 9] = fv[ii];
            }
        }
        __syncthreads();
    }

#pragma unroll
    for (int m = 0; m < 16; ++m) {
        const size_t ob = (size_t)(tok0 + m) * 768 + tid;
        out[ob]       = acc[0][m];
        out[ob + 256] = acc[1][m];
        out[ob + 512] = acc[2][m];
    }
}

// ---------------------------------------------------------------------------
extern "C" void kernel_launch(void* const* d_in, const int* in_sizes, int n_in,
                              void* d_out, int out_size, void* d_ws, size_t ws_size,
                              hipStream_t stream) {
    const float* x         = (const float*)d_in[0];
    const float* p1_kqv_w  = (const float*)d_in[1];
    const float* p1_kqv_b  = (const float*)d_in[2];
    const float* p1_proj_w = (const float*)d_in[3];
    const float* p1_proj_b = (const float*)d_in[4];
    const float* p1_ln1_g  = (const float*)d_in[5];
    const float* p1_ln1_b  = (const float*)d_in[6];
    const float* p1_ln2_g  = (const float*)d_in[7];
    const float* p1_ln2_b  = (const float*)d_in[8];
    const float* p1_m1_w   = (const float*)d_in[9];
    const float* p1_m1_b   = (const float*)d_in[10];
    const float* p1_m2_w   = (const float*)d_in[11];
    const float* p1_m2_b   = (const float*)d_in[12];
    const float* p1_rf     = (const float*)d_in[13];
    const float* p2_kqv_w  = (const float*)d_in[14];
    const float* p2_kqv_b  = (const float*)d_in[15];
    const float* p2_proj_w = (const float*)d_in[16];
    const float* p2_proj_b = (const float*)d_in[17];
    const float* p2_ln1_g  = (const float*)d_in[18];
    const float* p2_ln1_b  = (const float*)d_in[19];
    const float* p2_ln2_g  = (const float*)d_in[20];
    const float* p2_ln2_b  = (const float*)d_in[21];
    const float* p2_m1_w   = (const float*)d_in[22];
    const float* p2_m1_b   = (const float*)d_in[23];
    const float* p2_m2_w   = (const float*)d_in[24];
    const float* p2_m2_b   = (const float*)d_in[25];
    const float* p2_rf     = (const float*)d_in[26];
    const float* proj_w    = (const float*)d_in[27];
    const float* proj_b    = (const float*)d_in[28];

    float* ws = (float*)d_ws;
    size_t off = 0;
    float* ksum1 = ws + off; off += (size_t)NB * 32;
    float* kptv1 = ws + off; off += (size_t)NB * 64 * 32;
    float* ksum2 = ws + off; off += (size_t)NB * 32;
    float* kptv2 = ws + off; off += (size_t)NB * 64 * 32;
    const size_t zero_bytes = off * sizeof(float);
    float* kp1 = ws + off; off += (size_t)NB * T1 * 32;
    float* qp1 = ws + off; off += (size_t)NB * T1 * 32;
    float* v1  = ws + off; off += (size_t)NB * T1 * 64;
    float* o1  = ws + off; off += (size_t)NB * T1 * 64;
    float* w2g = ws + off; off += (size_t)D2 * 192;
    float* s2v = ws + off; off += 192;
    float* s3v = ws + off; off += 192;
    float* s2v1 = ws + off; off += 192;
    float* s3v1 = ws + off; off += 192;
    unsigned short* wt1h = (unsigned short*)(ws + off); off += (size_t)192 * KP1 / 2;
    unsigned short* wt1l = (unsigned short*)(ws + off); off += (size_t)192 * KP1 / 2;
    size_t off2 = 0;
    float* kp2 = kp1 + off2; off2 += (size_t)NB * T2 * 32;
    float* qp2 = kp1 + off2; off2 += (size_t)NB * T2 * 32;
    float* v2  = kp1 + off2; off2 += (size_t)NB * T2 * 64;
    float* o2  = kp1 + off2; off2 += (size_t)NB * T2 * 64;

    hipMemsetAsync(ws, 0, zero_bytes, stream);

    prep_scale<<<(D2 * 192 + 255) / 256, 256, 0, stream>>>(p2_kqv_w, p2_ln1_g, w2g, D2);
    prep_sums<<<1, 192, 0, stream>>>(p2_kqv_w, p2_ln1_g, p2_ln1_b, p2_kqv_b, s2v, s3v, D2);
    prep_sums<<<1, 192, 0, stream>>>(p1_kqv_w, p1_ln1_g, p1_ln1_b, p1_kqv_b, s2v1, s3v1, D1);
    prep_wt<<<(192 * KP1 + 255) / 256, 256, 0, stream>>>(p1_kqv_w, p1_ln1_g, wt1h, wt1l, D1, KP1);

    front1<<<NB * T1 / 32, 256, 0, stream>>>(x, wt1h, wt1l, s2v1, s3v1, p1_rf, kp1, qp1, v1);
    reduce_kv<T1, 14><<<NB * 14, 256, 0, stream>>>(kp1, v1, ksum1, kptv1);
    epilogue<T1><<<NB * T1 / 32, 128, 0, stream>>>(qp1, v1, ksum1, kptv1,
                                                   p1_proj_w, p1_proj_b, p1_ln2_g, p1_ln2_b,
                                                   p1_m1_w, p1_m1_b, p1_m2_w, p1_m2_b, o1);
    front2<<<NB * T2 / 16, 128, 0, stream>>>(o1, w2g, s2v, s3v, p2_rf, kp2, qp2, v2);
    reduce_kv<T2, 7><<<NB * 7, 256, 0, stream>>>(kp2, v2, ksum2, kptv2);
    epilogue<T2><<<NB * T2 / 32, 128, 0, stream>>>(qp2, v2, ksum2, kptv2,
                                                   p2_proj_w, p2_proj_b, p2_ln2_g, p2_ln2_b,
                                                   p2_m1_w, p2_m1_b, p2_m2_w, p2_m2_b, o2);
    final_proj<<<NB * T3 / 16, 256, 0, stream>>>(o2, proj_w, proj_b, (float*)d_out);
}

// Round 9
// 1227.976 us; speedup vs baseline: 1.0982x; 1.0982x over previous
//
#include <hip/hip_runtime.h>
#include <hip/hip_bf16.h>

#define NB 64
#define T1 3136
#define T2 784
#define T3 196
#define D1 147
#define D2 576

#define KP1 160   // padded K for front1 W^T (147 -> 160)
#define KS1 168   // front1 LDS A row stride (bf16): 84 dw = 20 mod 32, balanced
#define KS2 584   // front2/final LDS A row stride (bf16): 292 dw = 4 mod 32, balanced
#define KQS 68    // kqs row stride (floats)

typedef __attribute__((ext_vector_type(8))) short bf16x8;
typedef __attribute__((ext_vector_type(4))) float f32x4;

__device__ __forceinline__ float waveReduceSum(float v) {
#pragma unroll
    for (int off = 32; off > 0; off >>= 1) v += __shfl_down(v, off, 64);
    return __shfl(v, 0, 64);
}

__device__ __forceinline__ unsigned short f2bf(float v) {
    unsigned int u = __float_as_uint(v);
    return (unsigned short)((u + 0x7FFFu + ((u >> 16) & 1u)) >> 16);
}

// ---------------------------------------------------------------------------
// prep_sums: S2[c] = sum_d w[d,c]*g[d]; S3[c] = sum_d w[d,c]*b[d] + kqv_b[c].
// prep_wt:   split-bf16 W^T in PACKED tile layout: for element (n,k),
//            packed[ ((n>>4)*(K/32) + (k>>5))*512 + (((k>>3)&3)*16 + (n&15))*8
//                    + (k&7) ].
//            A wave's B-fragment (one 16-col tile, one 32-K step) is then a
//            single contiguous 1KB block read as lane*8 -- fully coalesced.
// ---------------------------------------------------------------------------
__global__ __launch_bounds__(192) void prep_sums(
    const float* __restrict__ w, const float* __restrict__ g,
    const float* __restrict__ bb, const float* __restrict__ kqvb,
    float* __restrict__ s2, float* __restrict__ s3, int D)
{
    const int col = threadIdx.x;
    float a2 = 0.f, a3 = 0.f;
    for (int d = 0; d < D; ++d) {
        const float wv = w[d * 192 + col];
        a2 += wv * g[d];
        a3 += wv * bb[d];
    }
    s2[col] = a2; s3[col] = a3 + kqvb[col];
}

__global__ __launch_bounds__(256) void prep_wt(
    const float* __restrict__ w, const float* __restrict__ g,
    unsigned short* __restrict__ hi, unsigned short* __restrict__ lo,
    int D, int K, int N)
{
    const int i = blockIdx.x * 256 + threadIdx.x;
    if (i >= N * K) return;
    const int n = i / K, k = i % K;
    const float v = (k < D) ? w[k * N + n] * (g ? g[k] : 1.f) : 0.f;
    const unsigned short h = f2bf(v);
    const float hf = __uint_as_float((unsigned int)h << 16);
    const size_t pidx = (size_t)((n >> 4) * (K >> 5) + (k >> 5)) * 512
                      + (size_t)((((k >> 3) & 3) * 16 + (n & 15)) * 8 + (k & 7));
    hi[pidx] = h;
    lo[pidx] = f2bf(v - hf);
}

// ---------------------------------------------------------------------------
// front1 v7 (MFMA, R8-validated fragment layout): 32 tokens, 256 thr = 4 waves.
// Changes vs R8: (a) packed B reads (1KB coalesced bursts), (b) xd pass reads
// kqs as float4 (R8's scalar reads were 8-way bank conflicts: stride 68 dw =
// 4 mod 32 put 64 lanes on 8 banks; b128 reads are balanced 8/bank = free).
// ---------------------------------------------------------------------------
__global__ __launch_bounds__(256) void front1(
    const float* __restrict__ x,
    const unsigned short* __restrict__ wt_hi,  // packed (192,KP1)
    const unsigned short* __restrict__ wt_lo,
    const float* __restrict__ s2v, const float* __restrict__ s3v,
    const float* __restrict__ rf,
    float* __restrict__ kp, float* __restrict__ qp,
    float* __restrict__ v_out)
{
    const int tok0 = blockIdx.x * 32;
    const int b = tok0 / T1;
    const int tbase = tok0 % T1;
    const int tid = threadIdx.x;
    const int wv = tid >> 6, l = tid & 63;
    const int l15 = l & 15, lg = l >> 4;

    __shared__ __align__(16) unsigned short Abuf[2 * 32 * KS1];  // 21504B
    __shared__ float ps_sum[256], ps_sq[256];
    __shared__ float mu_s[32], rs_s[32], xd_s[64];

    unsigned short* A_hi = Abuf;
    unsigned short* A_lo = Abuf + 32 * KS1;
    float* kqs = (float*)Abuf;                 // 64*KQS*4 = 17408B, aliases

    // --- fill: raw unfold -> bf16 hi/lo, LN stats in registers ---
    { const int m = tid & 31, j = tid >> 5;
      const int t = tbase + m;
      const int py = t / 56, px = t % 56;
      const int iy0 = py * 4 - 2, ix0 = px * 4 - 2;
      float sm = 0.f, sq = 0.f;
      for (int d = j; d < KS1; d += 8) {
          float val = 0.f;
          if (d < D1) {
              const int cc = d / 49, r = d % 49, ki = r / 7, kj = r % 7;
              const int iy = iy0 + ki, ix = ix0 + kj;
              if (iy >= 0 && iy < 224 && ix >= 0 && ix < 224)
                  val = x[((b * 3 + cc) * 224 + iy) * 224 + ix];
          }
          sm += val; sq += val * val;
          const unsigned short h = f2bf(val);
          A_hi[m * KS1 + d] = h;
          A_lo[m * KS1 + d] = f2bf(val - __uint_as_float((unsigned int)h << 16));
      }
      ps_sum[tid] = sm; ps_sq[tid] = sq; }
    __syncthreads();                           // barrier A
    if (tid < 32) {
        float s = 0.f, s2 = 0.f;
#pragma unroll
        for (int j2 = 0; j2 < 8; ++j2) { s += ps_sum[j2*32+tid]; s2 += ps_sq[j2*32+tid]; }
        const float mu = s * (1.f / D1);
        mu_s[tid] = mu; rs_s[tid] = rsqrtf(s2 * (1.f / D1) - mu * mu + 1e-5f);
    }

    // --- MFMA matvec: wave wv owns N-tiles {3wv..3wv+2} x M-tiles {0,1} ---
    f32x4 acc[2][3];
    { const f32x4 z = {0.f, 0.f, 0.f, 0.f};
#pragma unroll
      for (int mt = 0; mt < 2; ++mt)
#pragma unroll
        for (int nt = 0; nt < 3; ++nt) acc[mt][nt] = z; }

    for (int ks = 0; ks < 5; ++ks) {
        const int ko = ks * 32 + 8 * lg;
        const bf16x8 ah0 = *(const bf16x8*)&A_hi[l15 * KS1 + ko];
        const bf16x8 ah1 = *(const bf16x8*)&A_hi[(16 + l15) * KS1 + ko];
        const bf16x8 al0 = *(const bf16x8*)&A_lo[l15 * KS1 + ko];
        const bf16x8 al1 = *(const bf16x8*)&A_lo[(16 + l15) * KS1 + ko];
#pragma unroll
        for (int nt = 0; nt < 3; ++nt) {
            const size_t wo = ((size_t)((3 * wv + nt) * 5 + ks) << 9) + (size_t)(l << 3);
            const bf16x8 bh = *(const bf16x8*)&wt_hi[wo];
            const bf16x8 bl = *(const bf16x8*)&wt_lo[wo];
            acc[0][nt] = __builtin_amdgcn_mfma_f32_16x16x32_bf16(ah0, bh, acc[0][nt], 0, 0, 0);
            acc[1][nt] = __builtin_amdgcn_mfma_f32_16x16x32_bf16(ah1, bh, acc[1][nt], 0, 0, 0);
            acc[0][nt] = __builtin_amdgcn_mfma_f32_16x16x32_bf16(al0, bh, acc[0][nt], 0, 0, 0);
            acc[1][nt] = __builtin_amdgcn_mfma_f32_16x16x32_bf16(al1, bh, acc[1][nt], 0, 0, 0);
            acc[0][nt] = __builtin_amdgcn_mfma_f32_16x16x32_bf16(ah0, bl, acc[0][nt], 0, 0, 0);
            acc[1][nt] = __builtin_amdgcn_mfma_f32_16x16x32_bf16(ah1, bl, acc[1][nt], 0, 0, 0);
        }
    }
    __syncthreads();                           // barrier B: A dead, mu_s visible

    // --- fold-correction + scatter (C map m89: col=l15-based, row=4*lg+reg) ---
#pragma unroll
    for (int nt = 0; nt < 3; ++nt) {
        const int col = 48 * wv + 16 * nt + l15;
        const int third = col >> 6, cc = col & 63;
        const float s2c = s2v[col], s3c = s3v[col];
#pragma unroll
        for (int mt = 0; mt < 2; ++mt) {
#pragma unroll
            for (int r = 0; r < 4; ++r) {
                const int token = mt * 16 + 4 * lg + r;
                const float o = rs_s[token] * (acc[mt][nt][r] - mu_s[token] * s2c) + s3c;
                if (third == 2)
                    v_out[(size_t)(tok0 + token) * 64 + cc] = o;
                else
                    kqs[(third * 32 + token) * KQS + cc] = o;
            }
        }
    }
    __syncthreads();

    // xd = 0.5*||row||^2 via float4 reads (balanced banks)
    { const int hm = tid >> 2, seg = tid & 3;
      const float4* kr = (const float4*)&kqs[hm * KQS + seg * 16];
      float s = 0.f;
#pragma unroll
      for (int c4 = 0; c4 < 4; ++c4) {
          const float4 t4 = kr[c4];
          s += t4.x*t4.x + t4.y*t4.y + t4.z*t4.z + t4.w*t4.w;
      }
      ps_sum[tid] = s; }
    __syncthreads();
    if (tid < 64)
        xd_s[tid] = 0.5f * (ps_sum[4*tid] + ps_sum[4*tid+1] + ps_sum[4*tid+2] + ps_sum[4*tid+3]);
    __syncthreads();

    float4 rfr[16];
    { const float* rp = rf + (size_t)(tid & 31) * 64;
#pragma unroll
      for (int g = 0; g < 16; ++g) rfr[g] = *(const float4*)(rp + 4 * g); }

    for (int slot = tid; slot < 2048; slot += 256) {
        const int half = slot >> 10, rem = slot & 1023;
        const int m = rem >> 5, mrf = slot & 31;
        const float4* k4 = (const float4*)&kqs[(half * 32 + m) * KQS];
        float a = 0.f;
#pragma unroll
        for (int g = 0; g < 16; ++g) {
            const float4 kv = k4[g];
            a += rfr[g].x*kv.x + rfr[g].y*kv.y + rfr[g].z*kv.z + rfr[g].w*kv.w;
        }
        const float p = expf(a - xd_s[half * 32 + m]) * 0.1767766952966369f;
        (half ? qp : kp)[(size_t)(tok0 + m) * 32 + mrf] = p;
    }
}

// ---------------------------------------------------------------------------
// front2 v5 (MFMA): 16 tokens, 128 thr = 2 waves. unfold(3,2,1 over o1) ->
// bf16 hi/lo A in LDS (LN stats fused) -> split-bf16 MFMA (N=192: 6 N-tiles
// per wave; K=576: 18 steps) -> fold-correction -> prm_exp. Same fragment
// layout as front1 (HW-validated R8).
// ---------------------------------------------------------------------------
__global__ __launch_bounds__(128) void front2(
    const float* __restrict__ src,             // o1 (B*T1,64)
    const unsigned short* __restrict__ wt_hi,  // packed (192,576)
    const unsigned short* __restrict__ wt_lo,
    const float* __restrict__ s2v, const float* __restrict__ s3v,
    const float* __restrict__ rf,
    float* __restrict__ kp, float* __restrict__ qp,
    float* __restrict__ v_out)
{
    const int tok0 = blockIdx.x * 16;
    const int b = tok0 / T2;
    const int tbase = tok0 % T2;
    const int tid = threadIdx.x;
    const int wv = tid >> 6, l = tid & 63;
    const int l15 = l & 15, lg = l >> 4;

    __shared__ __align__(16) unsigned short Abuf[2 * 16 * KS2];  // 37376B
    __shared__ float ps_sum[128], ps_sq[128];
    __shared__ float mu_s[16], rs_s[16], xd_s[32];

    unsigned short* A_hi = Abuf;
    unsigned short* A_lo = Abuf + 16 * KS2;
    float* kqs = (float*)Abuf;                 // 32*KQS*4 = 8704B, aliases

    // --- fill: thread owns (token g16, channel-slice ch); 72 values ---
    { const int g16 = tid >> 3, ch = tid & 7;
      const int tmine = tbase + g16;
      const int py = tmine / 28, px = tmine % 28;
      const int iy0 = py * 2 - 1, ix0 = px * 2 - 1;
      const float* srcb = src + (size_t)b * T1 * 64 + ch;
      unsigned short* Ah = &A_hi[g16 * KS2];
      unsigned short* Al = &A_lo[g16 * KS2];
      float sm = 0.f, sq = 0.f;
#pragma unroll
      for (int r = 0; r < 9; ++r) {
          const int iy = iy0 + r / 3, ix = ix0 + r % 3;
          const bool ok = (iy >= 0 && iy < 56 && ix >= 0 && ix < 56);
          const float* sp = srcb + (size_t)(iy * 56 + ix) * 64;
#pragma unroll
          for (int c = 0; c < 8; ++c) {
              const float val = ok ? sp[c * 8] : 0.f;
              sm += val; sq += val * val;
              const int d = (c * 8 + ch) * 9 + r;
              const unsigned short h = f2bf(val);
              Ah[d] = h;
              Al[d] = f2bf(val - __uint_as_float((unsigned int)h << 16));
          }
      }
      ps_sum[tid] = sm; ps_sq[tid] = sq; }
    __syncthreads();                           // barrier A
    if (tid < 16) {
        float s = 0.f, s2 = 0.f;
#pragma unroll
        for (int j = 0; j < 8; ++j) { s += ps_sum[tid*8+j]; s2 += ps_sq[tid*8+j]; }
        const float mu = s * (1.f / D2);
        mu_s[tid] = mu; rs_s[tid] = rsqrtf(s2 * (1.f / D2) - mu * mu + 1e-5f);
    }

    // --- MFMA: wave wv owns cols [96wv, 96wv+96) via 6 N-tiles ---
    f32x4 acc[6];
    { const f32x4 z = {0.f, 0.f, 0.f, 0.f};
#pragma unroll
      for (int nt = 0; nt < 6; ++nt) acc[nt] = z; }

    for (int ks = 0; ks < 18; ++ks) {
        const int ko = ks * 32 + 8 * lg;
        const bf16x8 ah = *(const bf16x8*)&A_hi[l15 * KS2 + ko];
        const bf16x8 al = *(const bf16x8*)&A_lo[l15 * KS2 + ko];
#pragma unroll
        for (int nt = 0; nt < 6; ++nt) {
            const size_t wo = ((size_t)((6 * wv + nt) * 18 + ks) << 9) + (size_t)(l << 3);
            const bf16x8 bh = *(const bf16x8*)&wt_hi[wo];
            const bf16x8 bl = *(const bf16x8*)&wt_lo[wo];
            acc[nt] = __builtin_amdgcn_mfma_f32_16x16x32_bf16(ah, bh, acc[nt], 0, 0, 0);
            acc[nt] = __builtin_amdgcn_mfma_f32_16x16x32_bf16(al, bh, acc[nt], 0, 0, 0);
            acc[nt] = __builtin_amdgcn_mfma_f32_16x16x32_bf16(ah, bl, acc[nt], 0, 0, 0);
        }
    }
    __syncthreads();                           // barrier B: A dead, mu_s visible

    // --- fold-correction + scatter ---
#pragma unroll
    for (int nt = 0; nt < 6; ++nt) {
        const int col = 96 * wv + 16 * nt + l15;
        const int third = col >> 6, cc = col & 63;
        const float s2c = s2v[col], s3c = s3v[col];
#pragma unroll
        for (int r = 0; r < 4; ++r) {
            const int token = 4 * lg + r;
            const float o = rs_s[token] * (acc[nt][r] - mu_s[token] * s2c) + s3c;
            if (third == 2)
                v_out[(size_t)(tok0 + token) * 64 + cc] = o;
            else
                kqs[(third * 16 + token) * KQS + cc] = o;
        }
    }
    __syncthreads();

    { const int hm = tid >> 2, seg = tid & 3;
      const float4* kr = (const float4*)&kqs[hm * KQS + seg * 16];
      float s = 0.f;
#pragma unroll
      for (int c4 = 0; c4 < 4; ++c4) {
          const float4 t4 = kr[c4];
          s += t4.x*t4.x + t4.y*t4.y + t4.z*t4.z + t4.w*t4.w;
      }
      ps_sum[tid] = s; }
    __syncthreads();
    if (tid < 32)
        xd_s[tid] = 0.5f * (ps_sum[4*tid] + ps_sum[4*tid+1] + ps_sum[4*tid+2] + ps_sum[4*tid+3]);
    __syncthreads();

    float4 rfr[16];
    { const float* rp = rf + (size_t)(tid & 31) * 64;
#pragma unroll
      for (int g = 0; g < 16; ++g) rfr[g] = *(const float4*)(rp + 4 * g); }

    for (int slot = tid; slot < 1024; slot += 128) {
        const int half = slot >> 9, rem = slot & 511;
        const int m = rem >> 5, mrf = slot & 31;
        const float4* k4 = (const float4*)&kqs[(half * 16 + m) * KQS];
        float a = 0.f;
#pragma unroll
        for (int g = 0; g < 16; ++g) {
            const float4 kv = k4[g];
            a += rfr[g].x*kv.x + rfr[g].y*kv.y + rfr[g].z*kv.z + rfr[g].w*kv.w;
        }
        const float p = expf(a - xd_s[half * 16 + m]) * 0.1767766952966369f;
        (half ? qp : kp)[(size_t)(tok0 + m) * 32 + mrf] = p;
    }
}

// ---------------------------------------------------------------------------
// reduce_kv, split S-ways over T with atomics (ksum/kptv pre-zeroed)
// ---------------------------------------------------------------------------
template <int T, int S>
__global__ __launch_bounds__(256) void reduce_kv(
    const float* __restrict__ kp, const float* __restrict__ v,
    float* __restrict__ ksum, float* __restrict__ kptv)
{
    const int b = blockIdx.x / S, s = blockIdx.x % S;
    const int chunk = T / S;
    const int tid = threadIdx.x;
    __shared__ float kp_s[8][32];
    __shared__ float v_s[8][64];
    float acc[8] = {0.f, 0.f, 0.f, 0.f, 0.f, 0.f, 0.f, 0.f};
    float ks = 0.f;
    const int n = tid >> 2;
    const int mb = (tid & 3) * 8;
    const float* kpb = kp + (size_t)b * T * 32;
    const float* vb  = v  + (size_t)b * T * 64;

    for (int t0 = s * chunk; t0 < (s + 1) * chunk; t0 += 8) {
        kp_s[tid >> 5][tid & 31] = kpb[(t0 + (tid >> 5)) * 32 + (tid & 31)];
        {
            const int i0 = tid * 2, i1 = tid * 2 + 1;
            v_s[i0 >> 6][i0 & 63] = vb[(t0 + (i0 >> 6)) * 64 + (i0 & 63)];
            v_s[i1 >> 6][i1 & 63] = vb[(t0 + (i1 >> 6)) * 64 + (i1 & 63)];
        }
        __syncthreads();
#pragma unroll
        for (int tt = 0; tt < 8; ++tt) {
            const float vv = v_s[tt][n];
#pragma unroll
            for (int i = 0; i < 8; ++i) acc[i] += vv * kp_s[tt][mb + i];
        }
        if (tid < 32) {
#pragma unroll
            for (int tt = 0; tt < 8; ++tt) ks += kp_s[tt][tid];
        }
        __syncthreads();
    }
#pragma unroll
    for (int i = 0; i < 8; ++i) atomicAdd(&kptv[(b * 64 + n) * 32 + mb + i], acc[i]);
    if (tid < 32) atomicAdd(&ksum[b * 32 + tid], ks);
}

// ---------------------------------------------------------------------------
// epilogue: 128 threads = two independent 16-token tiles; per-sub ksum.
// ---------------------------------------------------------------------------
template <int T>
__global__ __launch_bounds__(128) void epilogue(
    const float* __restrict__ qp, const float* __restrict__ v,
    const float* __restrict__ ksum, const float* __restrict__ kptv,
    const float* __restrict__ proj_w, const float* __restrict__ proj_b,
    const float* __restrict__ ln2_g, const float* __restrict__ ln2_b,
    const float* __restrict__ m1_w, const float* __restrict__ m1_b,
    const float* __restrict__ m2_w, const float* __restrict__ m2_b,
    float* __restrict__ out)
{
    const int sub = threadIdx.x >> 6;
    const int e = threadIdx.x & 63;
    const int tok0 = blockIdx.x * 32 + sub * 16;
    const int b = tok0 / T;

    __shared__ __align__(16) float qp_s[2][16 * 36];
    __shared__ __align__(16) float buf[2][64 * 20];
    __shared__ float ks_s[2][32];
    __shared__ float D_s[2][16];

    for (int idx = e; idx < 512; idx += 64)
        qp_s[sub][(idx >> 5) * 36 + (idx & 31)] = qp[(size_t)tok0 * 32 + idx];
    if (e < 32) ks_s[sub][e] = ksum[b * 32 + e];
    __syncthreads();
    if (e < 16) {
        float D = 1e-8f;
        for (int r = 0; r < 32; ++r) D += qp_s[sub][e * 36 + r] * ks_s[sub][r];
        D_s[sub][e] = D;
    }
    float4 kv4[8];
#pragma unroll
    for (int g = 0; g < 8; ++g)
        kv4[g] = *(const float4*)&kptv[(size_t)(b * 64 + e) * 32 + 4 * g];
    __syncthreads();

    float ya[16];
#pragma unroll
    for (int m = 0; m < 16; ++m) {
        const float4* q4 = (const float4*)&qp_s[sub][m * 36];
        float a = 0.f;
#pragma unroll
        for (int g = 0; g < 8; ++g) {
            const float4 qv = q4[g];
            a += qv.x*kv4[g].x + qv.y*kv4[g].y + qv.z*kv4[g].z + qv.w*kv4[g].w;
        }
        ya[m] = a / D_s[sub][m];
    }
#pragma unroll
    for (int g = 0; g < 4; ++g)
        *(float4*)&buf[sub][e * 20 + 4*g] = make_float4(ya[4*g], ya[4*g+1], ya[4*g+2], ya[4*g+3]);
    __syncthreads();

    float y[16];
    { float acc2[16];
      const float pb = proj_b[e];
#pragma unroll
      for (int m = 0; m < 16; ++m) acc2[m] = pb;
      for (int j = 0; j < 64; ++j) {
          const float w = proj_w[j * 64 + e];
          const float4* a4 = (const float4*)&buf[sub][j * 20];
#pragma unroll
          for (int g = 0; g < 4; ++g) {
              const float4 av = a4[g];
              acc2[4*g+0] += av.x * w; acc2[4*g+1] += av.y * w;
              acc2[4*g+2] += av.z * w; acc2[4*g+3] += av.w * w;
          }
      }
#pragma unroll
      for (int m = 0; m < 16; ++m)
          y[m] = v[(size_t)(tok0 + m) * 64 + e] + acc2[m];
    }
    __syncthreads();

    { const float g2 = ln2_g[e], bb = ln2_b[e];
      float z[16];
#pragma unroll
      for (int m = 0; m < 16; ++m) {
          const float s  = waveReduceSum(y[m]);
          const float s2 = waveReduceSum(y[m] * y[m]);
          const float mu = s * (1.f / 64.f);
          const float var = s2 * (1.f / 64.f) - mu * mu;
          z[m] = (y[m] - mu) * rsqrtf(var + 1e-5f) * g2 + bb;
      }
#pragma unroll
      for (int g = 0; g < 4; ++g)
          *(float4*)&buf[sub][e * 20 + 4*g] = make_float4(z[4*g], z[4*g+1], z[4*g+2], z[4*g+3]);
    }
    __syncthreads();

    float h[16];
    { const float b1 = m1_b[e];
#pragma unroll
      for (int m = 0; m < 16; ++m) h[m] = b1;
      for (int j = 0; j < 64; ++j) {
          const float w = m1_w[j * 64 + e];
          const float4* a4 = (const float4*)&buf[sub][j * 20];
#pragma unroll
          for (int g = 0; g < 4; ++g) {
              const float4 av = a4[g];
              h[4*g+0] += av.x * w; h[4*g+1] += av.y * w;
              h[4*g+2] += av.z * w; h[4*g+3] += av.w * w;
          }
      }
#pragma unroll
      for (int m = 0; m < 16; ++m)
          h[m] = 0.5f * h[m] * (1.f + erff(h[m] * 0.7071067811865476f));
    }
    __syncthreads();
#pragma unroll
    for (int g = 0; g < 4; ++g)
        *(float4*)&buf[sub][e * 20 + 4*g] = make_float4(h[4*g], h[4*g+1], h[4*g+2], h[4*g+3]);
    __syncthreads();

    { const float b2v = m2_b[e];
      float acc4[16];
#pragma unroll
      for (int m = 0; m < 16; ++m) acc4[m] = b2v;
      for (int j = 0; j < 64; ++j) {
          const float w = m2_w[j * 64 + e];
          const float4* a4 = (const float4*)&buf[sub][j * 20];
#pragma unroll
          for (int g = 0; g < 4; ++g) {
              const float4 av = a4[g];
              acc4[4*g+0] += av.x * w; acc4[4*g+1] += av.y * w;
              acc4[4*g+2] += av.z * w; acc4[4*g+3] += av.w * w;
          }
      }
#pragma unroll
      for (int m = 0; m < 16; ++m)
          out[(size_t)(tok0 + m) * 64 + e] = y[m] + acc4[m];
    }
}

// ---------------------------------------------------------------------------
// final_proj v2 (MFMA): 16 tokens, 256 thr = 4 waves. unfold(3,2,1 over o2)
// -> bf16 hi/lo A in LDS -> split-bf16 MFMA (N=768: 12 N-tiles/wave; K=576)
// -> + bias -> out. No LN. Same fragment layout as front1.
// ---------------------------------------------------------------------------
__global__ __launch_bounds__(256) void final_proj(
    const float* __restrict__ o2,              // (B*T2,64)
    const unsigned short* __restrict__ wt_hi,  // packed (768,576)
    const unsigned short* __restrict__ wt_lo,
    const float* __restrict__ bias,            // (768)
    float* __restrict__ out)                   // (B*T3,768)
{
    const int tok0 = blockIdx.x * 16;
    const int tid = threadIdx.x;
    const int wv = tid >> 6, l = tid & 63;
    const int l15 = l & 15, lg = l >> 4;

    __shared__ __align__(16) unsigned short Abuf[2 * 16 * KS2];  // 37376B
    unsigned short* A_hi = Abuf;
    unsigned short* A_lo = Abuf + 16 * KS2;

    // --- fill: thread (cl = tid&15 channel, grp = tid>>4); 36 values ---
    { const int cl = tid & 15, grp = tid >> 4;
      for (int k = 0; k < 4; ++k) {
#pragma unroll
        for (int ii = 0; ii < 9; ++ii) {
            const int u = grp + ii * 16;       // u = m*9 + r
            const int m = u / 9, r = u % 9;
            const int tok = tok0 + m, bb = tok / T3, tt = tok % T3;
            const int py = tt / 14, px = tt % 14;
            const int iy = py * 2 - 1 + r / 3, ix = px * 2 - 1 + r % 3;
            float val = 0.f;
            if (iy >= 0 && iy < 28 && ix >= 0 && ix < 28)
                val = o2[(size_t)(bb * T2 + iy * 28 + ix) * 64 + k * 16 + cl];
            const int d = k * 144 + cl * 9 + r;
            const unsigned short h = f2bf(val);
            A_hi[m * KS2 + d] = h;
            A_lo[m * KS2 + d] = f2bf(val - __uint_as_float((unsigned int)h << 16));
        }
      }
    }
    __syncthreads();

    f32x4 acc[12];
    { const f32x4 z = {0.f, 0.f, 0.f, 0.f};
#pragma unroll
      for (int nt = 0; nt < 12; ++nt) acc[nt] = z; }

    for (int ks = 0; ks < 18; ++ks) {
        const int ko = ks * 32 + 8 * lg;
        const bf16x8 ah = *(const bf16x8*)&A_hi[l15 * KS2 + ko];
        const bf16x8 al = *(const bf16x8*)&A_lo[l15 * KS2 + ko];
#pragma unroll
        for (int nt = 0; nt < 12; ++nt) {
            const size_t wo = ((size_t)((12 * wv + nt) * 18 + ks) << 9) + (size_t)(l << 3);
            const bf16x8 bh = *(const bf16x8*)&wt_hi[wo];
            const bf16x8 bl = *(const bf16x8*)&wt_lo[wo];
            acc[nt] = __builtin_amdgcn_mfma_f32_16x16x32_bf16(ah, bh, acc[nt], 0, 0, 0);
            acc[nt] = __builtin_amdgcn_mfma_f32_16x16x32_bf16(al, bh, acc[nt], 0, 0, 0);
            acc[nt] = __builtin_amdgcn_mfma_f32_16x16x32_bf16(ah, bl, acc[nt], 0, 0, 0);
        }
    }

#pragma unroll
    for (int nt = 0; nt < 12; ++nt) {
        const int col = 192 * wv + 16 * nt + l15;
        const float bv = bias[col];
#pragma unroll
        for (int r = 0; r < 4; ++r) {
            const int token = 4 * lg + r;
            out[(size_t)(tok0 + token) * 768 + col] = acc[nt][r] + bv;
        }
    }
}

// ---------------------------------------------------------------------------
extern "C" void kernel_launch(void* const* d_in, const int* in_sizes, int n_in,
                              void* d_out, int out_size, void* d_ws, size_t ws_size,
                              hipStream_t stream) {
    const float* x         = (const float*)d_in[0];
    const float* p1_kqv_w  = (const float*)d_in[1];
    const float* p1_kqv_b  = (const float*)d_in[2];
    const float* p1_proj_w = (const float*)d_in[3];
    const float* p1_proj_b = (const float*)d_in[4];
    const float* p1_ln1_g  = (const float*)d_in[5];
    const float* p1_ln1_b  = (const float*)d_in[6];
    const float* p1_ln2_g  = (const float*)d_in[7];
    const float* p1_ln2_b  = (const float*)d_in[8];
    const float* p1_m1_w   = (const float*)d_in[9];
    const float* p1_m1_b   = (const float*)d_in[10];
    const float* p1_m2_w   = (const float*)d_in[11];
    const float* p1_m2_b   = (const float*)d_in[12];
    const float* p1_rf     = (const float*)d_in[13];
    const float* p2_kqv_w  = (const float*)d_in[14];
    const float* p2_kqv_b  = (const float*)d_in[15];
    const float* p2_proj_w = (const float*)d_in[16];
    const float* p2_proj_b = (const float*)d_in[17];
    const float* p2_ln1_g  = (const float*)d_in[18];
    const float* p2_ln1_b  = (const float*)d_in[19];
    const float* p2_ln2_g  = (const float*)d_in[20];
    const float* p2_ln2_b  = (const float*)d_in[21];
    const float* p2_m1_w   = (const float*)d_in[22];
    const float* p2_m1_b   = (const float*)d_in[23];
    const float* p2_m2_w   = (const float*)d_in[24];
    const float* p2_m2_b   = (const float*)d_in[25];
    const float* p2_rf     = (const float*)d_in[26];
    const float* proj_w    = (const float*)d_in[27];
    const float* proj_b    = (const float*)d_in[28];

    float* ws = (float*)d_ws;
    size_t off = 0;
    float* ksum1 = ws + off; off += (size_t)NB * 32;
    float* kptv1 = ws + off; off += (size_t)NB * 64 * 32;
    float* ksum2 = ws + off; off += (size_t)NB * 32;
    float* kptv2 = ws + off; off += (size_t)NB * 64 * 32;
    const size_t zero_bytes = off * sizeof(float);
    float* kp1 = ws + off; off += (size_t)NB * T1 * 32;
    float* qp1 = ws + off; off += (size_t)NB * T1 * 32;
    float* v1  = ws + off; off += (size_t)NB * T1 * 64;
    float* o1  = ws + off; off += (size_t)NB * T1 * 64;
    float* s2v = ws + off; off += 192;
    float* s3v = ws + off; off += 192;
    float* s2v1 = ws + off; off += 192;
    float* s3v1 = ws + off; off += 192;
    unsigned short* wt1h = (unsigned short*)(ws + off); off += (size_t)192 * KP1 / 2;
    unsigned short* wt1l = (unsigned short*)(ws + off); off += (size_t)192 * KP1 / 2;
    unsigned short* wt2h = (unsigned short*)(ws + off); off += (size_t)192 * 576 / 2;
    unsigned short* wt2l = (unsigned short*)(ws + off); off += (size_t)192 * 576 / 2;
    unsigned short* wtfh = (unsigned short*)(ws + off); off += (size_t)768 * 576 / 2;
    unsigned short* wtfl = (unsigned short*)(ws + off); off += (size_t)768 * 576 / 2;
    size_t off2 = 0;
    float* kp2 = kp1 + off2; off2 += (size_t)NB * T2 * 32;
    float* qp2 = kp1 + off2; off2 += (size_t)NB * T2 * 32;
    float* v2  = kp1 + off2; off2 += (size_t)NB * T2 * 64;
    float* o2  = kp1 + off2; off2 += (size_t)NB * T2 * 64;

    hipMemsetAsync(ws, 0, zero_bytes, stream);

    prep_sums<<<1, 192, 0, stream>>>(p2_kqv_w, p2_ln1_g, p2_ln1_b, p2_kqv_b, s2v, s3v, D2);
    prep_sums<<<1, 192, 0, stream>>>(p1_kqv_w, p1_ln1_g, p1_ln1_b, p1_kqv_b, s2v1, s3v1, D1);
    prep_wt<<<(192 * KP1 + 255) / 256, 256, 0, stream>>>(p1_kqv_w, p1_ln1_g, wt1h, wt1l, D1, KP1, 192);
    prep_wt<<<(192 * 576 + 255) / 256, 256, 0, stream>>>(p2_kqv_w, p2_ln1_g, wt2h, wt2l, D2, 576, 192);
    prep_wt<<<(768 * 576 + 255) / 256, 256, 0, stream>>>(proj_w, nullptr, wtfh, wtfl, D2, 576, 768);

    front1<<<NB * T1 / 32, 256, 0, stream>>>(x, wt1h, wt1l, s2v1, s3v1, p1_rf, kp1, qp1, v1);
    reduce_kv<T1, 14><<<NB * 14, 256, 0, stream>>>(kp1, v1, ksum1, kptv1);
    epilogue<T1><<<NB * T1 / 32, 128, 0, stream>>>(qp1, v1, ksum1, kptv1,
                                                   p1_proj_w, p1_proj_b, p1_ln2_g, p1_ln2_b,
                                                   p1_m1_w, p1_m1_b, p1_m2_w, p1_m2_b, o1);
    front2<<<NB * T2 / 16, 128, 0, stream>>>(o1, wt2h, wt2l, s2v, s3v, p2_rf, kp2, qp2, v2);
    reduce_kv<T2, 7><<<NB * 7, 256, 0, stream>>>(kp2, v2, ksum2, kptv2);
    epilogue<T2><<<NB * T2 / 32, 128, 0, stream>>>(qp2, v2, ksum2, kptv2,
                                                   p2_proj_w, p2_proj_b, p2_ln2_g, p2_ln2_b,
                                                   p2_m1_w, p2_m1_b, p2_m2_w, p2_m2_b, o2);
    final_proj<<<NB * T3 / 16, 256, 0, stream>>>(o2, wtfh, wtfl, proj_b, (float*)d_out);
}

// Round 10
// 961.766 us; speedup vs baseline: 1.4022x; 1.2768x over previous
//
#include <hip/hip_runtime.h>
#include <hip/hip_bf16.h>

#define NB 64
#define T1 3136
#define T2 784
#define T3 196
#define D1 147
#define D2 576

#define KP1 160   // padded K for front1 W^T (147 -> 160)
#define KS1 168   // front1 LDS A row stride (bf16): 84 dw = 20 mod 32, balanced
#define KS2 584   // front2/final LDS A row stride (bf16): 292 dw = 4 mod 32, balanced
#define KQS 68    // kqs row stride (floats)

typedef __attribute__((ext_vector_type(8))) short bf16x8;
typedef __attribute__((ext_vector_type(4))) float f32x4;

__device__ __forceinline__ float waveReduceSum(float v) {
#pragma unroll
    for (int off = 32; off > 0; off >>= 1) v += __shfl_down(v, off, 64);
    return __shfl(v, 0, 64);
}

__device__ __forceinline__ unsigned short f2bf(float v) {
    unsigned int u = __float_as_uint(v);
    return (unsigned short)((u + 0x7FFFu + ((u >> 16) & 1u)) >> 16);
}

// ---------------------------------------------------------------------------
// prep_sums v2 (parallel): R9's <<<1,192>>> version was the #1 hotspot
// (224us x2 -- 3 waves on ONE CU, 576 serial latency-bound loads). Now
// split into 16-row chunks across blocks: coalesced row reads, partial
// sums atomicAdd'ed into pre-zeroed s2/s3; block 0 adds kqv_b once.
// prep_wt: split-bf16 W^T in PACKED tile layout (1KB per (tile,ks) block).
// ---------------------------------------------------------------------------
__global__ __launch_bounds__(192) void prep_sums(
    const float* __restrict__ w, const float* __restrict__ g,
    const float* __restrict__ bb, const float* __restrict__ kqvb,
    float* __restrict__ s2, float* __restrict__ s3, int D)
{
    const int col = threadIdx.x;
    const int d0 = blockIdx.x * 16;
    const int d1 = (d0 + 16 < D) ? d0 + 16 : D;
    float a2 = 0.f, a3 = 0.f;
    for (int d = d0; d < d1; ++d) {
        const float wv = w[d * 192 + col];
        a2 += wv * g[d];
        a3 += wv * bb[d];
    }
    if (blockIdx.x == 0) a3 += kqvb[col];
    atomicAdd(&s2[col], a2);
    atomicAdd(&s3[col], a3);
}

__global__ __launch_bounds__(256) void prep_wt(
    const float* __restrict__ w, const float* __restrict__ g,
    unsigned short* __restrict__ hi, unsigned short* __restrict__ lo,
    int D, int K, int N)
{
    const int i = blockIdx.x * 256 + threadIdx.x;
    if (i >= N * K) return;
    const int n = i / K, k = i % K;
    const float v = (k < D) ? w[k * N + n] * (g ? g[k] : 1.f) : 0.f;
    const unsigned short h = f2bf(v);
    const float hf = __uint_as_float((unsigned int)h << 16);
    const size_t pidx = (size_t)((n >> 4) * (K >> 5) + (k >> 5)) * 512
                      + (size_t)((((k >> 3) & 3) * 16 + (n & 15)) * 8 + (k & 7));
    hi[pidx] = h;
    lo[pidx] = f2bf(v - hf);
}

// ---------------------------------------------------------------------------
// front1 v7 (MFMA, R8-validated fragment layout): 32 tokens, 256 thr = 4 waves.
// Packed B reads (1KB coalesced bursts); xd pass reads kqs as float4.
// ---------------------------------------------------------------------------
__global__ __launch_bounds__(256) void front1(
    const float* __restrict__ x,
    const unsigned short* __restrict__ wt_hi,  // packed (192,KP1)
    const unsigned short* __restrict__ wt_lo,
    const float* __restrict__ s2v, const float* __restrict__ s3v,
    const float* __restrict__ rf,
    float* __restrict__ kp, float* __restrict__ qp,
    float* __restrict__ v_out)
{
    const int tok0 = blockIdx.x * 32;
    const int b = tok0 / T1;
    const int tbase = tok0 % T1;
    const int tid = threadIdx.x;
    const int wv = tid >> 6, l = tid & 63;
    const int l15 = l & 15, lg = l >> 4;

    __shared__ __align__(16) unsigned short Abuf[2 * 32 * KS1];  // 21504B
    __shared__ float ps_sum[256], ps_sq[256];
    __shared__ float mu_s[32], rs_s[32], xd_s[64];

    unsigned short* A_hi = Abuf;
    unsigned short* A_lo = Abuf + 32 * KS1;
    float* kqs = (float*)Abuf;                 // 64*KQS*4 = 17408B, aliases

    // --- fill: raw unfold -> bf16 hi/lo, LN stats in registers ---
    { const int m = tid & 31, j = tid >> 5;
      const int t = tbase + m;
      const int py = t / 56, px = t % 56;
      const int iy0 = py * 4 - 2, ix0 = px * 4 - 2;
      float sm = 0.f, sq = 0.f;
      for (int d = j; d < KS1; d += 8) {
          float val = 0.f;
          if (d < D1) {
              const int cc = d / 49, r = d % 49, ki = r / 7, kj = r % 7;
              const int iy = iy0 + ki, ix = ix0 + kj;
              if (iy >= 0 && iy < 224 && ix >= 0 && ix < 224)
                  val = x[((b * 3 + cc) * 224 + iy) * 224 + ix];
          }
          sm += val; sq += val * val;
          const unsigned short h = f2bf(val);
          A_hi[m * KS1 + d] = h;
          A_lo[m * KS1 + d] = f2bf(val - __uint_as_float((unsigned int)h << 16));
      }
      ps_sum[tid] = sm; ps_sq[tid] = sq; }
    __syncthreads();                           // barrier A
    if (tid < 32) {
        float s = 0.f, s2 = 0.f;
#pragma unroll
        for (int j2 = 0; j2 < 8; ++j2) { s += ps_sum[j2*32+tid]; s2 += ps_sq[j2*32+tid]; }
        const float mu = s * (1.f / D1);
        mu_s[tid] = mu; rs_s[tid] = rsqrtf(s2 * (1.f / D1) - mu * mu + 1e-5f);
    }

    // --- MFMA matvec: wave wv owns N-tiles {3wv..3wv+2} x M-tiles {0,1} ---
    f32x4 acc[2][3];
    { const f32x4 z = {0.f, 0.f, 0.f, 0.f};
#pragma unroll
      for (int mt = 0; mt < 2; ++mt)
#pragma unroll
        for (int nt = 0; nt < 3; ++nt) acc[mt][nt] = z; }

    for (int ks = 0; ks < 5; ++ks) {
        const int ko = ks * 32 + 8 * lg;
        const bf16x8 ah0 = *(const bf16x8*)&A_hi[l15 * KS1 + ko];
        const bf16x8 ah1 = *(const bf16x8*)&A_hi[(16 + l15) * KS1 + ko];
        const bf16x8 al0 = *(const bf16x8*)&A_lo[l15 * KS1 + ko];
        const bf16x8 al1 = *(const bf16x8*)&A_lo[(16 + l15) * KS1 + ko];
#pragma unroll
        for (int nt = 0; nt < 3; ++nt) {
            const size_t wo = ((size_t)((3 * wv + nt) * 5 + ks) << 9) + (size_t)(l << 3);
            const bf16x8 bh = *(const bf16x8*)&wt_hi[wo];
            const bf16x8 bl = *(const bf16x8*)&wt_lo[wo];
            acc[0][nt] = __builtin_amdgcn_mfma_f32_16x16x32_bf16(ah0, bh, acc[0][nt], 0, 0, 0);
            acc[1][nt] = __builtin_amdgcn_mfma_f32_16x16x32_bf16(ah1, bh, acc[1][nt], 0, 0, 0);
            acc[0][nt] = __builtin_amdgcn_mfma_f32_16x16x32_bf16(al0, bh, acc[0][nt], 0, 0, 0);
            acc[1][nt] = __builtin_amdgcn_mfma_f32_16x16x32_bf16(al1, bh, acc[1][nt], 0, 0, 0);
            acc[0][nt] = __builtin_amdgcn_mfma_f32_16x16x32_bf16(ah0, bl, acc[0][nt], 0, 0, 0);
            acc[1][nt] = __builtin_amdgcn_mfma_f32_16x16x32_bf16(ah1, bl, acc[1][nt], 0, 0, 0);
        }
    }
    __syncthreads();                           // barrier B: A dead, mu_s visible

    // --- fold-correction + scatter (C map m89: col=l15-based, row=4*lg+reg) ---
#pragma unroll
    for (int nt = 0; nt < 3; ++nt) {
        const int col = 48 * wv + 16 * nt + l15;
        const int third = col >> 6, cc = col & 63;
        const float s2c = s2v[col], s3c = s3v[col];
#pragma unroll
        for (int mt = 0; mt < 2; ++mt) {
#pragma unroll
            for (int r = 0; r < 4; ++r) {
                const int token = mt * 16 + 4 * lg + r;
                const float o = rs_s[token] * (acc[mt][nt][r] - mu_s[token] * s2c) + s3c;
                if (third == 2)
                    v_out[(size_t)(tok0 + token) * 64 + cc] = o;
                else
                    kqs[(third * 32 + token) * KQS + cc] = o;
            }
        }
    }
    __syncthreads();

    // xd = 0.5*||row||^2 via float4 reads (balanced banks)
    { const int hm = tid >> 2, seg = tid & 3;
      const float4* kr = (const float4*)&kqs[hm * KQS + seg * 16];
      float s = 0.f;
#pragma unroll
      for (int c4 = 0; c4 < 4; ++c4) {
          const float4 t4 = kr[c4];
          s += t4.x*t4.x + t4.y*t4.y + t4.z*t4.z + t4.w*t4.w;
      }
      ps_sum[tid] = s; }
    __syncthreads();
    if (tid < 64)
        xd_s[tid] = 0.5f * (ps_sum[4*tid] + ps_sum[4*tid+1] + ps_sum[4*tid+2] + ps_sum[4*tid+3]);
    __syncthreads();

    float4 rfr[16];
    { const float* rp = rf + (size_t)(tid & 31) * 64;
#pragma unroll
      for (int g = 0; g < 16; ++g) rfr[g] = *(const float4*)(rp + 4 * g); }

    for (int slot = tid; slot < 2048; slot += 256) {
        const int half = slot >> 10, rem = slot & 1023;
        const int m = rem >> 5, mrf = slot & 31;
        const float4* k4 = (const float4*)&kqs[(half * 32 + m) * KQS];
        float a = 0.f;
#pragma unroll
        for (int g = 0; g < 16; ++g) {
            const float4 kv = k4[g];
            a += rfr[g].x*kv.x + rfr[g].y*kv.y + rfr[g].z*kv.z + rfr[g].w*kv.w;
        }
        const float p = expf(a - xd_s[half * 32 + m]) * 0.1767766952966369f;
        (half ? qp : kp)[(size_t)(tok0 + m) * 32 + mrf] = p;
    }
}

// ---------------------------------------------------------------------------
// front2 v5 (MFMA): 16 tokens, 128 thr = 2 waves. unfold(3,2,1 over o1) ->
// bf16 hi/lo A in LDS (LN stats fused) -> split-bf16 MFMA (N=192: 6 N-tiles
// per wave; K=576: 18 steps) -> fold-correction -> prm_exp.
// ---------------------------------------------------------------------------
__global__ __launch_bounds__(128) void front2(
    const float* __restrict__ src,             // o1 (B*T1,64)
    const unsigned short* __restrict__ wt_hi,  // packed (192,576)
    const unsigned short* __restrict__ wt_lo,
    const float* __restrict__ s2v, const float* __restrict__ s3v,
    const float* __restrict__ rf,
    float* __restrict__ kp, float* __restrict__ qp,
    float* __restrict__ v_out)
{
    const int tok0 = blockIdx.x * 16;
    const int b = tok0 / T2;
    const int tbase = tok0 % T2;
    const int tid = threadIdx.x;
    const int wv = tid >> 6, l = tid & 63;
    const int l15 = l & 15, lg = l >> 4;

    __shared__ __align__(16) unsigned short Abuf[2 * 16 * KS2];  // 37376B
    __shared__ float ps_sum[128], ps_sq[128];
    __shared__ float mu_s[16], rs_s[16], xd_s[32];

    unsigned short* A_hi = Abuf;
    unsigned short* A_lo = Abuf + 16 * KS2;
    float* kqs = (float*)Abuf;                 // 32*KQS*4 = 8704B, aliases

    // --- fill: thread owns (token g16, channel-slice ch); 72 values ---
    { const int g16 = tid >> 3, ch = tid & 7;
      const int tmine = tbase + g16;
      const int py = tmine / 28, px = tmine % 28;
      const int iy0 = py * 2 - 1, ix0 = px * 2 - 1;
      const float* srcb = src + (size_t)b * T1 * 64 + ch;
      unsigned short* Ah = &A_hi[g16 * KS2];
      unsigned short* Al = &A_lo[g16 * KS2];
      float sm = 0.f, sq = 0.f;
#pragma unroll
      for (int r = 0; r < 9; ++r) {
          const int iy = iy0 + r / 3, ix = ix0 + r % 3;
          const bool ok = (iy >= 0 && iy < 56 && ix >= 0 && ix < 56);
          const float* sp = srcb + (size_t)(iy * 56 + ix) * 64;
#pragma unroll
          for (int c = 0; c < 8; ++c) {
              const float val = ok ? sp[c * 8] : 0.f;
              sm += val; sq += val * val;
              const int d = (c * 8 + ch) * 9 + r;
              const unsigned short h = f2bf(val);
              Ah[d] = h;
              Al[d] = f2bf(val - __uint_as_float((unsigned int)h << 16));
          }
      }
      ps_sum[tid] = sm; ps_sq[tid] = sq; }
    __syncthreads();                           // barrier A
    if (tid < 16) {
        float s = 0.f, s2 = 0.f;
#pragma unroll
        for (int j = 0; j < 8; ++j) { s += ps_sum[tid*8+j]; s2 += ps_sq[tid*8+j]; }
        const float mu = s * (1.f / D2);
        mu_s[tid] = mu; rs_s[tid] = rsqrtf(s2 * (1.f / D2) - mu * mu + 1e-5f);
    }

    // --- MFMA: wave wv owns cols [96wv, 96wv+96) via 6 N-tiles ---
    f32x4 acc[6];
    { const f32x4 z = {0.f, 0.f, 0.f, 0.f};
#pragma unroll
      for (int nt = 0; nt < 6; ++nt) acc[nt] = z; }

    for (int ks = 0; ks < 18; ++ks) {
        const int ko = ks * 32 + 8 * lg;
        const bf16x8 ah = *(const bf16x8*)&A_hi[l15 * KS2 + ko];
        const bf16x8 al = *(const bf16x8*)&A_lo[l15 * KS2 + ko];
#pragma unroll
        for (int nt = 0; nt < 6; ++nt) {
            const size_t wo = ((size_t)((6 * wv + nt) * 18 + ks) << 9) + (size_t)(l << 3);
            const bf16x8 bh = *(const bf16x8*)&wt_hi[wo];
            const bf16x8 bl = *(const bf16x8*)&wt_lo[wo];
            acc[nt] = __builtin_amdgcn_mfma_f32_16x16x32_bf16(ah, bh, acc[nt], 0, 0, 0);
            acc[nt] = __builtin_amdgcn_mfma_f32_16x16x32_bf16(al, bh, acc[nt], 0, 0, 0);
            acc[nt] = __builtin_amdgcn_mfma_f32_16x16x32_bf16(ah, bl, acc[nt], 0, 0, 0);
        }
    }
    __syncthreads();                           // barrier B: A dead, mu_s visible

    // --- fold-correction + scatter ---
#pragma unroll
    for (int nt = 0; nt < 6; ++nt) {
        const int col = 96 * wv + 16 * nt + l15;
        const int third = col >> 6, cc = col & 63;
        const float s2c = s2v[col], s3c = s3v[col];
#pragma unroll
        for (int r = 0; r < 4; ++r) {
            const int token = 4 * lg + r;
            const float o = rs_s[token] * (acc[nt][r] - mu_s[token] * s2c) + s3c;
            if (third == 2)
                v_out[(size_t)(tok0 + token) * 64 + cc] = o;
            else
                kqs[(third * 16 + token) * KQS + cc] = o;
        }
    }
    __syncthreads();

    { const int hm = tid >> 2, seg = tid & 3;
      const float4* kr = (const float4*)&kqs[hm * KQS + seg * 16];
      float s = 0.f;
#pragma unroll
      for (int c4 = 0; c4 < 4; ++c4) {
          const float4 t4 = kr[c4];
          s += t4.x*t4.x + t4.y*t4.y + t4.z*t4.z + t4.w*t4.w;
      }
      ps_sum[tid] = s; }
    __syncthreads();
    if (tid < 32)
        xd_s[tid] = 0.5f * (ps_sum[4*tid] + ps_sum[4*tid+1] + ps_sum[4*tid+2] + ps_sum[4*tid+3]);
    __syncthreads();

    float4 rfr[16];
    { const float* rp = rf + (size_t)(tid & 31) * 64;
#pragma unroll
      for (int g = 0; g < 16; ++g) rfr[g] = *(const float4*)(rp + 4 * g); }

    for (int slot = tid; slot < 1024; slot += 128) {
        const int half = slot >> 9, rem = slot & 511;
        const int m = rem >> 5, mrf = slot & 31;
        const float4* k4 = (const float4*)&kqs[(half * 16 + m) * KQS];
        float a = 0.f;
#pragma unroll
        for (int g = 0; g < 16; ++g) {
            const float4 kv = k4[g];
            a += rfr[g].x*kv.x + rfr[g].y*kv.y + rfr[g].z*kv.z + rfr[g].w*kv.w;
        }
        const float p = expf(a - xd_s[half * 16 + m]) * 0.1767766952966369f;
        (half ? qp : kp)[(size_t)(tok0 + m) * 32 + mrf] = p;
    }
}

// ---------------------------------------------------------------------------
// reduce_kv, split S-ways over T with atomics (ksum/kptv pre-zeroed)
// ---------------------------------------------------------------------------
template <int T, int S>
__global__ __launch_bounds__(256) void reduce_kv(
    const float* __restrict__ kp, const float* __restrict__ v,
    float* __restrict__ ksum, float* __restrict__ kptv)
{
    const int b = blockIdx.x / S, s = blockIdx.x % S;
    const int chunk = T / S;
    const int tid = threadIdx.x;
    __shared__ float kp_s[8][32];
    __shared__ float v_s[8][64];
    float acc[8] = {0.f, 0.f, 0.f, 0.f, 0.f, 0.f, 0.f, 0.f};
    float ks = 0.f;
    const int n = tid >> 2;
    const int mb = (tid & 3) * 8;
    const float* kpb = kp + (size_t)b * T * 32;
    const float* vb  = v  + (size_t)b * T * 64;

    for (int t0 = s * chunk; t0 < (s + 1) * chunk; t0 += 8) {
        kp_s[tid >> 5][tid & 31] = kpb[(t0 + (tid >> 5)) * 32 + (tid & 31)];
        {
            const int i0 = tid * 2, i1 = tid * 2 + 1;
            v_s[i0 >> 6][i0 & 63] = vb[(t0 + (i0 >> 6)) * 64 + (i0 & 63)];
            v_s[i1 >> 6][i1 & 63] = vb[(t0 + (i1 >> 6)) * 64 + (i1 & 63)];
        }
        __syncthreads();
#pragma unroll
        for (int tt = 0; tt < 8; ++tt) {
            const float vv = v_s[tt][n];
#pragma unroll
            for (int i = 0; i < 8; ++i) acc[i] += vv * kp_s[tt][mb + i];
        }
        if (tid < 32) {
#pragma unroll
            for (int tt = 0; tt < 8; ++tt) ks += kp_s[tt][tid];
        }
        __syncthreads();
    }
#pragma unroll
    for (int i = 0; i < 8; ++i) atomicAdd(&kptv[(b * 64 + n) * 32 + mb + i], acc[i]);
    if (tid < 32) atomicAdd(&ksum[b * 32 + tid], ks);
}

// ---------------------------------------------------------------------------
// epilogue: 128 threads = two independent 16-token tiles; per-sub ksum.
// ---------------------------------------------------------------------------
template <int T>
__global__ __launch_bounds__(128) void epilogue(
    const float* __restrict__ qp, const float* __restrict__ v,
    const float* __restrict__ ksum, const float* __restrict__ kptv,
    const float* __restrict__ proj_w, const float* __restrict__ proj_b,
    const float* __restrict__ ln2_g, const float* __restrict__ ln2_b,
    const float* __restrict__ m1_w, const float* __restrict__ m1_b,
    const float* __restrict__ m2_w, const float* __restrict__ m2_b,
    float* __restrict__ out)
{
    const int sub = threadIdx.x >> 6;
    const int e = threadIdx.x & 63;
    const int tok0 = blockIdx.x * 32 + sub * 16;
    const int b = tok0 / T;

    __shared__ __align__(16) float qp_s[2][16 * 36];
    __shared__ __align__(16) float buf[2][64 * 20];
    __shared__ float ks_s[2][32];
    __shared__ float D_s[2][16];

    for (int idx = e; idx < 512; idx += 64)
        qp_s[sub][(idx >> 5) * 36 + (idx & 31)] = qp[(size_t)tok0 * 32 + idx];
    if (e < 32) ks_s[sub][e] = ksum[b * 32 + e];
    __syncthreads();
    if (e < 16) {
        float D = 1e-8f;
        for (int r = 0; r < 32; ++r) D += qp_s[sub][e * 36 + r] * ks_s[sub][r];
        D_s[sub][e] = D;
    }
    float4 kv4[8];
#pragma unroll
    for (int g = 0; g < 8; ++g)
        kv4[g] = *(const float4*)&kptv[(size_t)(b * 64 + e) * 32 + 4 * g];
    __syncthreads();

    float ya[16];
#pragma unroll
    for (int m = 0; m < 16; ++m) {
        const float4* q4 = (const float4*)&qp_s[sub][m * 36];
        float a = 0.f;
#pragma unroll
        for (int g = 0; g < 8; ++g) {
            const float4 qv = q4[g];
            a += qv.x*kv4[g].x + qv.y*kv4[g].y + qv.z*kv4[g].z + qv.w*kv4[g].w;
        }
        ya[m] = a / D_s[sub][m];
    }
#pragma unroll
    for (int g = 0; g < 4; ++g)
        *(float4*)&buf[sub][e * 20 + 4*g] = make_float4(ya[4*g], ya[4*g+1], ya[4*g+2], ya[4*g+3]);
    __syncthreads();

    float y[16];
    { float acc2[16];
      const float pb = proj_b[e];
#pragma unroll
      for (int m = 0; m < 16; ++m) acc2[m] = pb;
      for (int j = 0; j < 64; ++j) {
          const float w = proj_w[j * 64 + e];
          const float4* a4 = (const float4*)&buf[sub][j * 20];
#pragma unroll
          for (int g = 0; g < 4; ++g) {
              const float4 av = a4[g];
              acc2[4*g+0] += av.x * w; acc2[4*g+1] += av.y * w;
              acc2[4*g+2] += av.z * w; acc2[4*g+3] += av.w * w;
          }
      }
#pragma unroll
      for (int m = 0; m < 16; ++m)
          y[m] = v[(size_t)(tok0 + m) * 64 + e] + acc2[m];
    }
    __syncthreads();

    { const float g2 = ln2_g[e], bb = ln2_b[e];
      float z[16];
#pragma unroll
      for (int m = 0; m < 16; ++m) {
          const float s  = waveReduceSum(y[m]);
          const float s2 = waveReduceSum(y[m] * y[m]);
          const float mu = s * (1.f / 64.f);
          const float var = s2 * (1.f / 64.f) - mu * mu;
          z[m] = (y[m] - mu) * rsqrtf(var + 1e-5f) * g2 + bb;
      }
#pragma unroll
      for (int g = 0; g < 4; ++g)
          *(float4*)&buf[sub][e * 20 + 4*g] = make_float4(z[4*g], z[4*g+1], z[4*g+2], z[4*g+3]);
    }
    __syncthreads();

    float h[16];
    { const float b1 = m1_b[e];
#pragma unroll
      for (int m = 0; m < 16; ++m) h[m] = b1;
      for (int j = 0; j < 64; ++j) {
          const float w = m1_w[j * 64 + e];
          const float4* a4 = (const float4*)&buf[sub][j * 20];
#pragma unroll
          for (int g = 0; g < 4; ++g) {
              const float4 av = a4[g];
              h[4*g+0] += av.x * w; h[4*g+1] += av.y * w;
              h[4*g+2] += av.z * w; h[4*g+3] += av.w * w;
          }
      }
#pragma unroll
      for (int m = 0; m < 16; ++m)
          h[m] = 0.5f * h[m] * (1.f + erff(h[m] * 0.7071067811865476f));
    }
    __syncthreads();
#pragma unroll
    for (int g = 0; g < 4; ++g)
        *(float4*)&buf[sub][e * 20 + 4*g] = make_float4(h[4*g], h[4*g+1], h[4*g+2], h[4*g+3]);
    __syncthreads();

    { const float b2v = m2_b[e];
      float acc4[16];
#pragma unroll
      for (int m = 0; m < 16; ++m) acc4[m] = b2v;
      for (int j = 0; j < 64; ++j) {
          const float w = m2_w[j * 64 + e];
          const float4* a4 = (const float4*)&buf[sub][j * 20];
#pragma unroll
          for (int g = 0; g < 4; ++g) {
              const float4 av = a4[g];
              acc4[4*g+0] += av.x * w; acc4[4*g+1] += av.y * w;
              acc4[4*g+2] += av.z * w; acc4[4*g+3] += av.w * w;
          }
      }
#pragma unroll
      for (int m = 0; m < 16; ++m)
          out[(size_t)(tok0 + m) * 64 + e] = y[m] + acc4[m];
    }
}

// ---------------------------------------------------------------------------
// final_proj v2 (MFMA): 16 tokens, 256 thr = 4 waves. unfold(3,2,1 over o2)
// -> bf16 hi/lo A in LDS -> split-bf16 MFMA (N=768: 12 N-tiles/wave; K=576)
// -> + bias -> out.
// ---------------------------------------------------------------------------
__global__ __launch_bounds__(256) void final_proj(
    const float* __restrict__ o2,              // (B*T2,64)
    const unsigned short* __restrict__ wt_hi,  // packed (768,576)
    const unsigned short* __restrict__ wt_lo,
    const float* __restrict__ bias,            // (768)
    float* __restrict__ out)                   // (B*T3,768)
{
    const int tok0 = blockIdx.x * 16;
    const int tid = threadIdx.x;
    const int wv = tid >> 6, l = tid & 63;
    const int l15 = l & 15, lg = l >> 4;

    __shared__ __align__(16) unsigned short Abuf[2 * 16 * KS2];  // 37376B
    unsigned short* A_hi = Abuf;
    unsigned short* A_lo = Abuf + 16 * KS2;

    // --- fill: thread (cl = tid&15 channel, grp = tid>>4); 36 values ---
    { const int cl = tid & 15, grp = tid >> 4;
      for (int k = 0; k < 4; ++k) {
#pragma unroll
        for (int ii = 0; ii < 9; ++ii) {
            const int u = grp + ii * 16;       // u = m*9 + r
            const int m = u / 9, r = u % 9;
            const int tok = tok0 + m, bb = tok / T3, tt = tok % T3;
            const int py = tt / 14, px = tt % 14;
            const int iy = py * 2 - 1 + r / 3, ix = px * 2 - 1 + r % 3;
            float val = 0.f;
            if (iy >= 0 && iy < 28 && ix >= 0 && ix < 28)
                val = o2[(size_t)(bb * T2 + iy * 28 + ix) * 64 + k * 16 + cl];
            const int d = k * 144 + cl * 9 + r;
            const unsigned short h = f2bf(val);
            A_hi[m * KS2 + d] = h;
            A_lo[m * KS2 + d] = f2bf(val - __uint_as_float((unsigned int)h << 16));
        }
      }
    }
    __syncthreads();

    f32x4 acc[12];
    { const f32x4 z = {0.f, 0.f, 0.f, 0.f};
#pragma unroll
      for (int nt = 0; nt < 12; ++nt) acc[nt] = z; }

    for (int ks = 0; ks < 18; ++ks) {
        const int ko = ks * 32 + 8 * lg;
        const bf16x8 ah = *(const bf16x8*)&A_hi[l15 * KS2 + ko];
        const bf16x8 al = *(const bf16x8*)&A_lo[l15 * KS2 + ko];
#pragma unroll
        for (int nt = 0; nt < 12; ++nt) {
            const size_t wo = ((size_t)((12 * wv + nt) * 18 + ks) << 9) + (size_t)(l << 3);
            const bf16x8 bh = *(const bf16x8*)&wt_hi[wo];
            const bf16x8 bl = *(const bf16x8*)&wt_lo[wo];
            acc[nt] = __builtin_amdgcn_mfma_f32_16x16x32_bf16(ah, bh, acc[nt], 0, 0, 0);
            acc[nt] = __builtin_amdgcn_mfma_f32_16x16x32_bf16(al, bh, acc[nt], 0, 0, 0);
            acc[nt] = __builtin_amdgcn_mfma_f32_16x16x32_bf16(ah, bl, acc[nt], 0, 0, 0);
        }
    }

#pragma unroll
    for (int nt = 0; nt < 12; ++nt) {
        const int col = 192 * wv + 16 * nt + l15;
        const float bv = bias[col];
#pragma unroll
        for (int r = 0; r < 4; ++r) {
            const int token = 4 * lg + r;
            out[(size_t)(tok0 + token) * 768 + col] = acc[nt][r] + bv;
        }
    }
}

// ---------------------------------------------------------------------------
extern "C" void kernel_launch(void* const* d_in, const int* in_sizes, int n_in,
                              void* d_out, int out_size, void* d_ws, size_t ws_size,
                              hipStream_t stream) {
    const float* x         = (const float*)d_in[0];
    const float* p1_kqv_w  = (const float*)d_in[1];
    const float* p1_kqv_b  = (const float*)d_in[2];
    const float* p1_proj_w = (const float*)d_in[3];
    const float* p1_proj_b = (const float*)d_in[4];
    const float* p1_ln1_g  = (const float*)d_in[5];
    const float* p1_ln1_b  = (const float*)d_in[6];
    const float* p1_ln2_g  = (const float*)d_in[7];
    const float* p1_ln2_b  = (const float*)d_in[8];
    const float* p1_m1_w   = (const float*)d_in[9];
    const float* p1_m1_b   = (const float*)d_in[10];
    const float* p1_m2_w   = (const float*)d_in[11];
    const float* p1_m2_b   = (const float*)d_in[12];
    const float* p1_rf     = (const float*)d_in[13];
    const float* p2_kqv_w  = (const float*)d_in[14];
    const float* p2_kqv_b  = (const float*)d_in[15];
    const float* p2_proj_w = (const float*)d_in[16];
    const float* p2_proj_b = (const float*)d_in[17];
    const float* p2_ln1_g  = (const float*)d_in[18];
    const float* p2_ln1_b  = (const float*)d_in[19];
    const float* p2_ln2_g  = (const float*)d_in[20];
    const float* p2_ln2_b  = (const float*)d_in[21];
    const float* p2_m1_w   = (const float*)d_in[22];
    const float* p2_m1_b   = (const float*)d_in[23];
    const float* p2_m2_w   = (const float*)d_in[24];
    const float* p2_m2_b   = (const float*)d_in[25];
    const float* p2_rf     = (const float*)d_in[26];
    const float* proj_w    = (const float*)d_in[27];
    const float* proj_b    = (const float*)d_in[28];

    float* ws = (float*)d_ws;
    size_t off = 0;
    float* ksum1 = ws + off; off += (size_t)NB * 32;
    float* kptv1 = ws + off; off += (size_t)NB * 64 * 32;
    float* ksum2 = ws + off; off += (size_t)NB * 32;
    float* kptv2 = ws + off; off += (size_t)NB * 64 * 32;
    float* s2v = ws + off; off += 192;      // in zeroed region: prep_sums atomics
    float* s3v = ws + off; off += 192;
    float* s2v1 = ws + off; off += 192;
    float* s3v1 = ws + off; off += 192;
    const size_t zero_bytes = off * sizeof(float);
    float* kp1 = ws + off; off += (size_t)NB * T1 * 32;
    float* qp1 = ws + off; off += (size_t)NB * T1 * 32;
    float* v1  = ws + off; off += (size_t)NB * T1 * 64;
    float* o1  = ws + off; off += (size_t)NB * T1 * 64;
    unsigned short* wt1h = (unsigned short*)(ws + off); off += (size_t)192 * KP1 / 2;
    unsigned short* wt1l = (unsigned short*)(ws + off); off += (size_t)192 * KP1 / 2;
    unsigned short* wt2h = (unsigned short*)(ws + off); off += (size_t)192 * 576 / 2;
    unsigned short* wt2l = (unsigned short*)(ws + off); off += (size_t)192 * 576 / 2;
    unsigned short* wtfh = (unsigned short*)(ws + off); off += (size_t)768 * 576 / 2;
    unsigned short* wtfl = (unsigned short*)(ws + off); off += (size_t)768 * 576 / 2;
    size_t off2 = 0;
    float* kp2 = kp1 + off2; off2 += (size_t)NB * T2 * 32;
    float* qp2 = kp1 + off2; off2 += (size_t)NB * T2 * 32;
    float* v2  = kp1 + off2; off2 += (size_t)NB * T2 * 64;
    float* o2  = kp1 + off2; off2 += (size_t)NB * T2 * 64;

    hipMemsetAsync(ws, 0, zero_bytes, stream);

    prep_sums<<<(D2 + 15) / 16, 192, 0, stream>>>(p2_kqv_w, p2_ln1_g, p2_ln1_b, p2_kqv_b, s2v, s3v, D2);
    prep_sums<<<(D1 + 15) / 16, 192, 0, stream>>>(p1_kqv_w, p1_ln1_g, p1_ln1_b, p1_kqv_b, s2v1, s3v1, D1);
    prep_wt<<<(192 * KP1 + 255) / 256, 256, 0, stream>>>(p1_kqv_w, p1_ln1_g, wt1h, wt1l, D1, KP1, 192);
    prep_wt<<<(192 * 576 + 255) / 256, 256, 0, stream>>>(p2_kqv_w, p2_ln1_g, wt2h, wt2l, D2, 576, 192);
    prep_wt<<<(768 * 576 + 255) / 256, 256, 0, stream>>>(proj_w, nullptr, wtfh, wtfl, D2, 576, 768);

    front1<<<NB * T1 / 32, 256, 0, stream>>>(x, wt1h, wt1l, s2v1, s3v1, p1_rf, kp1, qp1, v1);
    reduce_kv<T1, 14><<<NB * 14, 256, 0, stream>>>(kp1, v1, ksum1, kptv1);
    epilogue<T1><<<NB * T1 / 32, 128, 0, stream>>>(qp1, v1, ksum1, kptv1,
                                                   p1_proj_w, p1_proj_b, p1_ln2_g, p1_ln2_b,
                                                   p1_m1_w, p1_m1_b, p1_m2_w, p1_m2_b, o1);
    front2<<<NB * T2 / 16, 128, 0, stream>>>(o1, wt2h, wt2l, s2v, s3v, p2_rf, kp2, qp2, v2);
    reduce_kv<T2, 7><<<NB * 7, 256, 0, stream>>>(kp2, v2, ksum2, kptv2);
    epilogue<T2><<<NB * T2 / 32, 128, 0, stream>>>(qp2, v2, ksum2, kptv2,
                                                   p2_proj_w, p2_proj_b, p2_ln2_g, p2_ln2_b,
                                                   p2_m1_w, p2_m1_b, p2_m2_w, p2_m2_b, o2);
    final_proj<<<NB * T3 / 16, 256, 0, stream>>>(o2, wtfh, wtfl, proj_b, (float*)d_out);
}